// Round 4
// baseline (488.528 us; speedup 1.0000x reference)
//
#include <hip/hip_runtime.h>

typedef _Float16 h16;
typedef __attribute__((ext_vector_type(8))) _Float16 half8;
typedef __attribute__((ext_vector_type(4))) _Float16 half4;
typedef __attribute__((ext_vector_type(2))) _Float16 half2v;
typedef __attribute__((ext_vector_type(4))) float float4v;

typedef const __attribute__((address_space(1))) unsigned char gu8;
typedef __attribute__((address_space(3))) unsigned char su8;

#define NTOK  32400   // 5*60*108
#define NPTOK 720     // 5*12*12
#define CDIM  512
#define SCALE 0.08838834764831845f
#define ZROW  NTOK            // zero row index in unified K/V buffers
#define PROW  (NTOK + 1)      // pooled rows start

// valid-index table for the rolled halo (nonzero of stacked tl,tr,bl,br 5x9 masks)
__constant__ int VIR_TBL[120] = {
  5,6,7,8, 14,15,16,17, 23,24,25,26,
  27,28,29,30,31,32,33,34,35, 36,37,38,39,40,41,42,43,44,
  45,46,47,48, 54,55,56,57, 63,64,65,66,
  72,73,74,75,76,77,78,79,80, 81,82,83,84,85,86,87,88,89,
  90,91,92,93,94,95,96,97,98, 99,100,101,102,103,104,105,106,107,
  113,114,115,116, 122,123,124,125, 131,132,133,134,
  135,136,137,138,139,140,141,142,143, 144,145,146,147,148,149,150,151,152,
  153,154,155,156, 162,163,164,165, 171,172,173,174
};

// ---------------- token row table + per-step valid mask -------------------
__global__ __launch_bounds__(256) void build_tok(int* __restrict__ Tok,
                                                 int* __restrict__ WMask) {
  const int win = blockIdx.x;
  const int wy = win / 12, wx = win % 12;
  for (int kidx = threadIdx.x; kidx < 1056; kidx += 256) {
    int e;
    if (kidx < 225) {
      int t = kidx / 45, pos = kidx % 45;
      int y = wy * 5 + pos / 9, x = wx * 9 + pos % 9;
      e = (t * 60 + y) * 108 + x;
    } else if (kidx < 825) {
      int jj = kidx - 225;
      int t = jj / 120, m = jj % 120;
      int vir = VIR_TBL[m];
      int p = vir / 45, pos = vir % 45;
      int r = pos / 9, c = pos % 9;
      int sy = (p < 2) ? -2 : 2;
      int sx = (p & 1) ? 4 : -4;
      int y = (wy * 5 + r - sy + 60) % 60;
      int x = (wx * 9 + c - sx + 108) % 108;
      e = (t * 60 + y) * 108 + x;
    } else if (kidx < 1050) {
      int jp = kidx - 825;
      int t = jp / 45, pos = jp % 45;
      int py = wy + pos / 9 - 2;
      int px = wx + pos % 9 - 4;
      e = (py >= 0 && py < 12 && px >= 0 && px < 12)
            ? (PROW + t * 144 + py * 12 + px) : ZROW;
    } else {
      e = ZROW;
    }
    Tok[win * 1056 + kidx] = e;
  }
  if (threadIdx.x < 33) {
    int m = 0;
#pragma unroll 1
    for (int r = 0; r < 32; r++) {
      int kidx = threadIdx.x * 32 + r;
      bool v;
      if (kidx < 825) v = true;
      else if (kidx < 1050) {
        int jp = kidx - 825, pos = jp % 45;
        int py = wy + pos / 9 - 2, px = wx + pos % 9 - 4;
        v = (py >= 0 && py < 12 && px >= 0 && px < 12);
      } else v = false;
      m |= (v ? 1 : 0) << r;
    }
    WMask[win * 33 + threadIdx.x] = m;
  }
}

// ---------------- zero_rows: clear the unified-buffer zero rows ----------
__global__ __launch_bounds__(256) void zero_rows(h16* __restrict__ a,
                                                 h16* __restrict__ b) {
  for (int k = threadIdx.x; k < 512; k += 256) {
    a[(size_t)ZROW * CDIM + k] = (h16)0.f;
    b[(size_t)ZROW * CDIM + k] = (h16)0.f;
  }
}

// ------------- transpose_cvt: src R x C fp32 -> dst C x R f16 ------------
__global__ __launch_bounds__(256) void transpose_cvt(const float* __restrict__ src,
                                                     h16* __restrict__ dst,
                                                     int R, int C) {
  __shared__ float T[32][33];
  const int t = threadIdx.x;
  const int ct = blockIdx.x * 32;
  const int rt = blockIdx.y * 32;
  const int c = t & 31, r0 = (t >> 5) * 4;
#pragma unroll
  for (int i = 0; i < 4; i++)
    T[r0 + i][c] = src[(size_t)(rt + r0 + i) * C + ct + c];
  __syncthreads();
#pragma unroll
  for (int i = 0; i < 4; i++)
    dst[(size_t)(ct + r0 + i) * R + rt + c] = (h16)T[c][r0 + i];
}

// ------------- cvt_x0: fp32 (NTOK x 512) -> f16 --------------------------
__global__ __launch_bounds__(256) void cvt_x0(const float* __restrict__ src,
                                              h16* __restrict__ dst) {
  const int total = NTOK * CDIM / 8;
  for (int i = blockIdx.x * 256 + threadIdx.x; i < total; i += gridDim.x * 256) {
    const float4* s = (const float4*)(src + (size_t)i * 8);
    float4 f0 = s[0], f1 = s[1];
    half8 h;
    h[0] = (h16)f0.x; h[1] = (h16)f0.y; h[2] = (h16)f0.z; h[3] = (h16)f0.w;
    h[4] = (h16)f1.x; h[5] = (h16)f1.y; h[6] = (h16)f1.z; h[7] = (h16)f1.w;
    *(half8*)(dst + (size_t)i * 8) = h;
  }
}

// ------------ MFMA GEMM LDS shapes (double-buffered staging) -------------
struct __align__(16) Stage2 { h16 Ah[2][128][32]; h16 Bh[2][128][32]; };  // 32 KB
union __align__(16) GemmLDSQ { Stage2 s; h16 Cs[128][136]; };             // 34.8 KB

// GEMM 1: Xh(f16) @ Wqkvt^T + b -> Q,K,V (f16). Bt layout [n][k].
// 2-phase pipeline: issue next tile's global_load_lds BEFORE computing the
// current tile; the post-compute barrier drains the loads (T3 minimum-2ph).
// A-tail rows (>= NTOK) clamp gather source (outputs masked at store).
__global__ __launch_bounds__(256) void gemm_qkv_mfma(
    const h16* __restrict__ A, const h16* __restrict__ Bt,
    const float* __restrict__ bias,
    h16* __restrict__ Q, h16* __restrict__ K, h16* __restrict__ V)
{
  __shared__ GemmLDSQ u;
  const int tid = threadIdx.x;
  const int lane = tid & 63, wv = tid >> 6;
  const int col = lane & 15, quad = lane >> 4;
  const int bn = blockIdx.x, bm = blockIdx.y;
  const int mo = (wv & 1) * 64, no = (wv >> 1) * 64;

  float4v acc[4][4];
#pragma unroll
  for (int i = 0; i < 4; i++)
#pragma unroll
    for (int j = 0; j < 4; j++) acc[i][j] = (float4v){0.f, 0.f, 0.f, 0.f};

  const int lrow = lane >> 2, lcol = (lane & 3) * 8;
  const int arow = bm * 128 + wv * 32 + lrow;
  const int ar = arow < NTOK ? arow : (NTOK - 1);
  const int ar2 = (arow + 16) < NTOK ? (arow + 16) : (NTOK - 1);
  const h16* Ag  = A + (size_t)ar * 512 + lcol;
  const h16* Ag2 = A + (size_t)ar2 * 512 + lcol;
  const h16* Bg  = Bt + (size_t)(bn * 128 + wv * 32 + lrow) * 512 + lcol;

#define STAGE_G(buf, k0) do {                                              \
    su8* Al = (su8*)&u.s.Ah[buf][wv * 32][0];                              \
    su8* Bl = (su8*)&u.s.Bh[buf][wv * 32][0];                              \
    __builtin_amdgcn_global_load_lds((gu8*)(Ag + (k0)),            Al,        16, 0, 0); \
    __builtin_amdgcn_global_load_lds((gu8*)(Ag2 + (k0)),           Al + 1024, 16, 0, 0); \
    __builtin_amdgcn_global_load_lds((gu8*)(Bg + (k0)),            Bl,        16, 0, 0); \
    __builtin_amdgcn_global_load_lds((gu8*)(Bg + (k0) + 16 * 512), Bl + 1024, 16, 0, 0); \
  } while (0)

  STAGE_G(0, 0);
  __syncthreads();   // drains vmcnt: buf0 ready
  for (int kt = 0; kt < 16; kt++) {
    const int cur = kt & 1;
    if (kt + 1 < 16) STAGE_G(cur ^ 1, (kt + 1) * 32);   // in flight over compute

    half8 afr[4], bfr[4];
#pragma unroll
    for (int i = 0; i < 4; i++)
      afr[i] = *(const half8*)&u.s.Ah[cur][mo + i * 16 + col][quad * 8];
#pragma unroll
    for (int j = 0; j < 4; j++)
      bfr[j] = *(const half8*)&u.s.Bh[cur][no + j * 16 + col][quad * 8];
#pragma unroll
    for (int i = 0; i < 4; i++)
#pragma unroll
      for (int j = 0; j < 4; j++)
        acc[i][j] = __builtin_amdgcn_mfma_f32_16x16x32_f16(afr[i], bfr[j], acc[i][j], 0, 0, 0);
    __syncthreads();  // drains next-tile loads + this tile's lgkm
  }

  float bv[4];
#pragma unroll
  for (int j = 0; j < 4; j++) bv[j] = bias[bn * 128 + no + j * 16 + col];
#pragma unroll
  for (int i = 0; i < 4; i++)
#pragma unroll
    for (int j = 0; j < 4; j++)
#pragma unroll
      for (int r = 0; r < 4; r++)
        u.Cs[mo + i * 16 + quad * 4 + r][no + j * 16 + col] = (h16)(acc[i][j][r] + bv[j]);
  __syncthreads();

  const int row_l = tid >> 1, halfseg = (tid & 1) * 64;
  const int row_g = bm * 128 + row_l;
  const int jsel = bn >> 2;
  const int ch0 = (bn & 3) * 128 + halfseg;
  h16* dst = (jsel == 0) ? Q : (jsel == 1) ? K : V;
  if (row_g < NTOK) {
#pragma unroll
    for (int c = 0; c < 64; c += 8)
      *(half8*)&dst[(size_t)row_g * 512 + ch0 + c] = *(const half8*)&u.Cs[row_l][halfseg + c];
  }
}

// GEMM 3: AO(f16) @ Wprojt^T + b -> out (fp32). Same 2-phase pipeline.
__global__ __launch_bounds__(256) void gemm_proj_mfma(
    const h16* __restrict__ A, const h16* __restrict__ Bt,
    const float* __restrict__ bias, float* __restrict__ out)
{
  __shared__ Stage2 s;
  const int tid = threadIdx.x;
  const int lane = tid & 63, wv = tid >> 6;
  const int col = lane & 15, quad = lane >> 4;
  const int bn = blockIdx.x, bm = blockIdx.y;
  const int mo = (wv & 1) * 64, no = (wv >> 1) * 64;

  float4v acc[4][4];
#pragma unroll
  for (int i = 0; i < 4; i++)
#pragma unroll
    for (int j = 0; j < 4; j++) acc[i][j] = (float4v){0.f, 0.f, 0.f, 0.f};

  const int lrow = lane >> 2, lcol = (lane & 3) * 8;
  const int arow = bm * 128 + wv * 32 + lrow;
  const int ar = arow < NTOK ? arow : (NTOK - 1);
  const int ar2 = (arow + 16) < NTOK ? (arow + 16) : (NTOK - 1);
  const h16* Ag  = A + (size_t)ar * 512 + lcol;
  const h16* Ag2 = A + (size_t)ar2 * 512 + lcol;
  const h16* Bg  = Bt + (size_t)(bn * 128 + wv * 32 + lrow) * 512 + lcol;

#define STAGE_P(buf, k0) do {                                              \
    su8* Al = (su8*)&s.Ah[buf][wv * 32][0];                                \
    su8* Bl = (su8*)&s.Bh[buf][wv * 32][0];                                \
    __builtin_amdgcn_global_load_lds((gu8*)(Ag + (k0)),            Al,        16, 0, 0); \
    __builtin_amdgcn_global_load_lds((gu8*)(Ag2 + (k0)),           Al + 1024, 16, 0, 0); \
    __builtin_amdgcn_global_load_lds((gu8*)(Bg + (k0)),            Bl,        16, 0, 0); \
    __builtin_amdgcn_global_load_lds((gu8*)(Bg + (k0) + 16 * 512), Bl + 1024, 16, 0, 0); \
  } while (0)

  STAGE_P(0, 0);
  __syncthreads();
  for (int kt = 0; kt < 16; kt++) {
    const int cur = kt & 1;
    if (kt + 1 < 16) STAGE_P(cur ^ 1, (kt + 1) * 32);

    half8 afr[4], bfr[4];
#pragma unroll
    for (int i = 0; i < 4; i++)
      afr[i] = *(const half8*)&s.Ah[cur][mo + i * 16 + col][quad * 8];
#pragma unroll
    for (int j = 0; j < 4; j++)
      bfr[j] = *(const half8*)&s.Bh[cur][no + j * 16 + col][quad * 8];
#pragma unroll
    for (int i = 0; i < 4; i++)
#pragma unroll
      for (int j = 0; j < 4; j++)
        acc[i][j] = __builtin_amdgcn_mfma_f32_16x16x32_f16(afr[i], bfr[j], acc[i][j], 0, 0, 0);
    __syncthreads();
  }

  float bv[4];
#pragma unroll
  for (int j = 0; j < 4; j++) bv[j] = bias[bn * 128 + no + j * 16 + col];
#pragma unroll
  for (int i = 0; i < 4; i++) {
#pragma unroll
    for (int r = 0; r < 4; r++) {
      int row_g = bm * 128 + mo + i * 16 + quad * 4 + r;
      if (row_g < NTOK) {
#pragma unroll
        for (int j = 0; j < 4; j++)
          out[(size_t)row_g * 512 + bn * 128 + no + j * 16 + col] = acc[i][j][r] + bv[j];
      }
    }
  }
}

// ---------------- GEMM 2: pooled x1 @ W_qkv[:,512:] -> Kp,Vp -------------
__global__ __launch_bounds__(256) void gemm_pooled(
    const float* __restrict__ A, const float* __restrict__ B,
    const float* __restrict__ bias,
    h16* __restrict__ Kp, h16* __restrict__ Vp)
{
  __shared__ float As[64][17];
  __shared__ float Bs[16][64];
  const int tid = threadIdx.x;
  const int bm = blockIdx.x, bn = blockIdx.y;
  const int tm = tid >> 4, tn = tid & 15;
  const int lrow = tid >> 2, lk = (tid & 3) * 4;
  const int brow = tid >> 4, bcol = (tid & 15) * 4;
  float acc[4][4] = {};
  const int orow = bm * 64 + lrow;
  int srow = 0;
  if (orow < NPTOK) { int t = orow / 144, rem = orow % 144; srow = rem * 5 + t; }
  const float* Ap = A + (size_t)srow * 512 + lk;
  const float* Bp = B + (size_t)brow * 1536 + 512 + bn * 64 + bcol;

  for (int k0 = 0; k0 < 512; k0 += 16) {
    float4 av = make_float4(0.f, 0.f, 0.f, 0.f);
    if (orow < NPTOK) av = *(const float4*)(Ap + k0);
    float4 bv = *(const float4*)(Bp + (size_t)k0 * 1536);
    As[lrow][lk + 0] = av.x; As[lrow][lk + 1] = av.y;
    As[lrow][lk + 2] = av.z; As[lrow][lk + 3] = av.w;
    *(float4*)&Bs[brow][bcol] = bv;
    __syncthreads();
#pragma unroll
    for (int kk = 0; kk < 16; kk++) {
      float a[4];
#pragma unroll
      for (int i = 0; i < 4; i++) a[i] = As[tm * 4 + i][kk];
      float4 b = *(const float4*)&Bs[kk][tn * 4];
#pragma unroll
      for (int i = 0; i < 4; i++) {
        acc[i][0] = fmaf(a[i], b.x, acc[i][0]);
        acc[i][1] = fmaf(a[i], b.y, acc[i][1]);
        acc[i][2] = fmaf(a[i], b.z, acc[i][2]);
        acc[i][3] = fmaf(a[i], b.w, acc[i][3]);
      }
    }
    __syncthreads();
  }
  const int nl = bn * 64 + tn * 4;
  const int j = nl >> 9;
  const int ch = nl & 511;
  h16* dst = (j == 0) ? Kp : Vp;
#pragma unroll
  for (int i = 0; i < 4; i++) {
    int r = bm * 64 + tm * 4 + i;
    if (r < NPTOK) {
#pragma unroll
      for (int c = 0; c < 4; c++)
        dst[(size_t)r * 512 + ch + c] = (h16)(acc[i][c] + bias[512 + nl + c]);
    }
  }
}

// ---------------- Attention v6: 8-wave blocks, shared K/V staging --------
// grid (144 win, 4 head), 512 threads = 8 waves; wave owns 2 q-tiles
// (tiles 0..15, 256 rows >= 225). Merging the old qg dimension halves the
// redundant K/V global gathers + LDS staging per unit of q-work.
// Staging roles (512 lanes): K: lane -> (row tid>>4, 8-ch seg tid&15), one
// b128 each. V: lane -> (token-pair tid>>5, 4-ch grp tid&31), 4 half2v
// transposed writes; new mapping is 2-way-bank (free) vs old 4-way.
// LDS double-buffer, 1 barrier/step; setprio around MFMA (T5).
// launch_bounds(512,2): 256-VGPR cap -- never constrains below working set
// (round-2 lesson: capping below working set -> scratch spill, 2.6x).
__global__ __launch_bounds__(512, 2) void attn_kernel(
    const h16* __restrict__ Qh, const h16* __restrict__ KhU,
    const h16* __restrict__ VhU, const int* __restrict__ Tok,
    const int* __restrict__ WMask, h16* __restrict__ AOh)
{
  __shared__ __align__(16) h16 Ks[2][32 * 136];
  __shared__ __align__(16) h16 Vt[2][128 * 40];

  const int tid = threadIdx.x;
  const int lane = tid & 63;
  const int wv = tid >> 6;          // 0..7
  const int win = blockIdx.x;
  const int head = blockIdx.y;
  const int wy = win / 12, wx = win % 12;
  const int col = lane & 15;
  const int quad = lane >> 4;
  const int* TokW = Tok + win * 1056;
  const int* WMaskW = WMask + win * 33;

  // ---- Q fragments for 2 tiles ----
  half8 qfrag[2][4];
  const int tile0 = wv * 2;
#pragma unroll
  for (int tt = 0; tt < 2; tt++) {
    int qrow = (tile0 + tt) * 16 + col;
    if (qrow < 225) {
      int t = qrow / 45, pos = qrow % 45;
      int y = wy * 5 + pos / 9, x = wx * 9 + pos % 9;
      const h16* qsrc = Qh + (size_t)((t * 60 + y) * 108 + x) * CDIM + head * 128;
#pragma unroll
      for (int dc = 0; dc < 4; dc++)
        qfrag[tt][dc] = *(const half8*)(qsrc + dc * 32 + quad * 8);
    } else {
#pragma unroll
      for (int dc = 0; dc < 4; dc++)
#pragma unroll
        for (int jj = 0; jj < 8; jj++) qfrag[tt][dc][jj] = (h16)0.f;
    }
  }

  float4v O[2][8];
#pragma unroll
  for (int tt = 0; tt < 2; tt++)
#pragma unroll
    for (int i = 0; i < 8; i++) O[tt][i] = (float4v){0.f, 0.f, 0.f, 0.f};
  float lp[2] = {0.f, 0.f};

  // staging roles (512 threads)
  const int krow = tid >> 4, kseg = tid & 15;
  const int vrp  = tid >> 5, vcg6 = tid & 31;
  const int kch = head * 128 + kseg * 8;
  const int vch = head * 128 + vcg6 * 4;
  const int rp  = (vrp + ((vcg6 >> 1) & 3) * 4) & 15;

  // ---- prologue: gather+stage step0 into buf0; gather step1 into regs ----
  {
    half8 kc = *(const half8*)(KhU + (size_t)TokW[krow] * CDIM + kch);
    half4 va = *(const half4*)(VhU + (size_t)TokW[2 * vrp] * CDIM + vch);
    half4 vb = *(const half4*)(VhU + (size_t)TokW[2 * vrp + 1] * CDIM + vch);
    *(half8*)&Ks[0][krow * 136 + kseg * 8] = kc;
#pragma unroll
    for (int i = 0; i < 4; i++) {
      half2v w; w[0] = va[i]; w[1] = vb[i];
      *(half2v*)&Vt[0][(vcg6 * 4 + i) * 40 + rp * 2] = w;
    }
  }
  half8 kn; half4 van, vbn;
  kn  = *(const half8*)(KhU + (size_t)TokW[32 + krow] * CDIM + kch);
  van = *(const half4*)(VhU + (size_t)TokW[32 + 2 * vrp] * CDIM + vch);
  vbn = *(const half4*)(VhU + (size_t)TokW[32 + 2 * vrp + 1] * CDIM + vch);
  // token ring: slot (s&1) holds rows for step s+2 at the top of step s
  int tokK[2], tokVa[2], tokVb[2];
  tokK[0] = TokW[64 + krow]; tokVa[0] = TokW[64 + 2 * vrp]; tokVb[0] = TokW[64 + 2 * vrp + 1];
  tokK[1] = TokW[96 + krow]; tokVa[1] = TokW[96 + 2 * vrp]; tokVb[1] = TokW[96 + 2 * vrp + 1];
  __syncthreads();

  for (int step = 0; step < 33; ++step) {
    const int cur = step & 1;

    // ---- stage NEXT tile into the other buffer (overlaps compute) ----
    if (step + 1 < 33) {
      *(half8*)&Ks[cur ^ 1][krow * 136 + kseg * 8] = kn;
      h16* VtN = Vt[cur ^ 1];
#pragma unroll
      for (int i = 0; i < 4; i++) {
        half2v w; w[0] = van[i]; w[1] = vbn[i];
        *(half2v*)&VtN[(vcg6 * 4 + i) * 40 + rp * 2] = w;
      }
    }
    // ---- issue gathers for step+2 (latency hidden under compute) ----
    if (step + 2 < 33) {
      kn  = *(const half8*)(KhU + (size_t)tokK[cur] * CDIM + kch);
      van = *(const half4*)(VhU + (size_t)tokVa[cur] * CDIM + vch);
      vbn = *(const half4*)(VhU + (size_t)tokVb[cur] * CDIM + vch);
      if (step + 4 < 33) {
        tokK[cur]  = TokW[(step + 4) * 32 + krow];
        tokVa[cur] = TokW[(step + 4) * 32 + 2 * vrp];
        tokVb[cur] = TokW[(step + 4) * 32 + 2 * vrp + 1];
      }
    }

    const int mask = WMaskW[step];
    const h16* KsC = Ks[cur];
    const h16* VtC = Vt[cur];

    // ---- S^T = K.Q^T (operand-swapped) ----
    float4v s0[2] = {{0.f,0.f,0.f,0.f},{0.f,0.f,0.f,0.f}};
    float4v s1[2] = {{0.f,0.f,0.f,0.f},{0.f,0.f,0.f,0.f}};
    __builtin_amdgcn_s_setprio(1);
#pragma unroll
    for (int dc = 0; dc < 4; dc++) {
      half8 a0 = *(const half8*)&KsC[col * 136 + dc * 32 + quad * 8];
      half8 a1 = *(const half8*)&KsC[(col + 16) * 136 + dc * 32 + quad * 8];
#pragma unroll
      for (int tt = 0; tt < 2; tt++) {
        s0[tt] = __builtin_amdgcn_mfma_f32_16x16x32_f16(a0, qfrag[tt][dc], s0[tt], 0, 0, 0);
        s1[tt] = __builtin_amdgcn_mfma_f32_16x16x32_f16(a1, qfrag[tt][dc], s1[tt], 0, 0, 0);
      }
    }
    __builtin_amdgcn_s_setprio(0);

    // ---- fixed-max softmax + P^T -> A-frag via shuffles ----
    half8 pfrag[2];
    const int srcA = (((quad << 1) & 3) << 4) | col;
    const int srcB = ((((quad << 1) + 1) & 3) << 4) | col;
    const bool hi = quad >= 2;
#pragma unroll
    for (int tt = 0; tt < 2; tt++) {
      float pm0[4], pm1[4];
#pragma unroll
      for (int i = 0; i < 4; i++) {
        int r = quad * 4 + i;
        float e0 = __expf(s0[tt][i] * SCALE);
        float e1 = __expf(s1[tt][i] * SCALE);
        pm0[i] = ((mask >> r) & 1) ? e0 : 0.f;
        pm1[i] = ((mask >> (16 + r)) & 1) ? e1 : 0.f;
        lp[tt] += pm0[i] + pm1[i];
      }
      float g00 = __builtin_bit_cast(float, __builtin_amdgcn_cvt_pkrtz(pm0[0], pm0[1]));
      float g01 = __builtin_bit_cast(float, __builtin_amdgcn_cvt_pkrtz(pm0[2], pm0[3]));
      float g10 = __builtin_bit_cast(float, __builtin_amdgcn_cvt_pkrtz(pm1[0], pm1[1]));
      float g11 = __builtin_bit_cast(float, __builtin_amdgcn_cvt_pkrtz(pm1[2], pm1[3]));
      float a0 = __shfl(g00, srcA), a1 = __shfl(g01, srcA);
      float a2 = __shfl(g00, srcB), a3 = __shfl(g01, srcB);
      float b0 = __shfl(g10, srcA), b1 = __shfl(g11, srcA);
      float b2 = __shfl(g10, srcB), b3 = __shfl(g11, srcB);
      float4v pf;
      pf[0] = hi ? b0 : a0;
      pf[1] = hi ? b1 : a1;
      pf[2] = hi ? b2 : a2;
      pf[3] = hi ? b3 : a3;
      pfrag[tt] = __builtin_bit_cast(half8, pf);
    }

    // ---- O += P V (shared V fragments, single b128 each) ----
    __builtin_amdgcn_s_setprio(1);
#pragma unroll
    for (int dt = 0; dt < 8; dt++) {
      int ch = dt * 16 + col;
      int g4 = ((dt * 2 + (col >> 3)) & 3) * 4;
      int x0 = (quad * 4 + g4) & 15;
      half8 vf = *(const half8*)&VtC[ch * 40 + x0 * 2];
#pragma unroll
      for (int tt = 0; tt < 2; tt++)
        O[tt][dt] = __builtin_amdgcn_mfma_f32_16x16x32_f16(pfrag[tt], vf, O[tt][dt], 0, 0, 0);
    }
    __builtin_amdgcn_s_setprio(0);

    // single barrier: covers RAW on buf[cur^1] writes and WAR on buf[cur] reads
    __syncthreads();
  }

  // ---- epilogue: deferred l reduction + store ----
#pragma unroll
  for (int tt = 0; tt < 2; tt++) {
    float l_all = lp[tt];
    l_all += __shfl_xor(l_all, 16);
    l_all += __shfl_xor(l_all, 32);
#pragma unroll
    for (int i = 0; i < 4; i++) {
      int qr = (tile0 + tt) * 16 + quad * 4 + i;
      if (qr < 225) {
        float invl = __builtin_amdgcn_rcpf(__shfl(l_all, quad * 4 + i));
        h16* dst = AOh + ((size_t)win * 225 + qr) * CDIM + head * 128 + col;
#pragma unroll
        for (int dt = 0; dt < 8; dt++)
          dst[dt * 16] = (h16)(O[tt][dt][i] * invl);
      }
    }
  }
}

extern "C" void kernel_launch(void* const* d_in, const int* in_sizes, int n_in,
                              void* d_out, int out_size, void* d_ws, size_t ws_size,
                              hipStream_t stream) {
  const float* x0    = (const float*)d_in[0];
  const float* x1    = (const float*)d_in[1];
  const float* Wqkv  = (const float*)d_in[2];
  const float* bqkv  = (const float*)d_in[3];
  const float* Wproj = (const float*)d_in[4];
  const float* bproj = (const float*)d_in[5];
  float* out = (float*)d_out;

  const size_t NU = (size_t)(NTOK + 1 + NPTOK);   // unified K/V row count
  h16* Qh   = (h16*)d_ws;
  h16* KhU  = Qh + (size_t)NTOK * CDIM;
  h16* VhU  = KhU + NU * CDIM;
  // Rh: NTOK x 512 f16 region, time-shared: x0h (GEMM1 input) then AOh
  h16* Rh   = VhU + NU * CDIM;
  h16* Wqkvt  = Rh + (size_t)NTOK * CDIM;         // 1536 x 512
  h16* Wprojt = Wqkvt + (size_t)1536 * 512;       // 512 x 512
  int* Tok    = (int*)(Wprojt + (size_t)512 * 512);  // 144 x 1056
  int* WMaskP = Tok + (size_t)144 * 1056;            // 144 x 33

  build_tok<<<144, 256, 0, stream>>>(Tok, WMaskP);
  zero_rows<<<1, 256, 0, stream>>>(KhU, VhU);
  transpose_cvt<<<dim3(48, 16), 256, 0, stream>>>(Wqkv, Wqkvt, 512, 1536);
  transpose_cvt<<<dim3(16, 16), 256, 0, stream>>>(Wproj, Wprojt, 512, 512);
  cvt_x0<<<2048, 256, 0, stream>>>(x0, Rh);

  gemm_qkv_mfma<<<dim3(12, 254), 256, 0, stream>>>(Rh, Wqkvt, bqkv, Qh, KhU, VhU);
  gemm_pooled<<<dim3(12, 16), 256, 0, stream>>>(x1, Wqkv, bqkv,
                                                KhU + (size_t)PROW * CDIM,
                                                VhU + (size_t)PROW * CDIM);
  attn_kernel<<<dim3(144, 4), 512, 0, stream>>>(Qh, KhU, VhU, Tok, WMaskP, Rh);
  gemm_proj_mfma<<<dim3(4, 254), 256, 0, stream>>>(Rh, Wprojt, bproj, out);
}

// Round 5
// 467.420 us; speedup vs baseline: 1.0452x; 1.0452x over previous
//
#include <hip/hip_runtime.h>

typedef _Float16 h16;
typedef __attribute__((ext_vector_type(8))) _Float16 half8;
typedef __attribute__((ext_vector_type(2))) _Float16 half2v;
typedef __attribute__((ext_vector_type(4))) float float4v;

typedef const __attribute__((address_space(1))) unsigned char gu8;
typedef __attribute__((address_space(3))) unsigned char su8;

#define NTOK  32400   // 5*60*108
#define NPTOK 720     // 5*12*12
#define CDIM  512
#define SCALE 0.08838834764831845f
#define ZROW  NTOK            // zero row index in unified K/V buffers
#define PROW  (NTOK + 1)      // pooled rows start

// valid-index table for the rolled halo (nonzero of stacked tl,tr,bl,br 5x9 masks)
__constant__ int VIR_TBL[120] = {
  5,6,7,8, 14,15,16,17, 23,24,25,26,
  27,28,29,30,31,32,33,34,35, 36,37,38,39,40,41,42,43,44,
  45,46,47,48, 54,55,56,57, 63,64,65,66,
  72,73,74,75,76,77,78,79,80, 81,82,83,84,85,86,87,88,89,
  90,91,92,93,94,95,96,97,98, 99,100,101,102,103,104,105,106,107,
  113,114,115,116, 122,123,124,125, 131,132,133,134,
  135,136,137,138,139,140,141,142,143, 144,145,146,147,148,149,150,151,152,
  153,154,155,156, 162,163,164,165, 171,172,173,174
};

// ---------------- token row table + per-step valid mask -------------------
__global__ __launch_bounds__(256) void build_tok(int* __restrict__ Tok,
                                                 int* __restrict__ WMask) {
  const int win = blockIdx.x;
  const int wy = win / 12, wx = win % 12;
  for (int kidx = threadIdx.x; kidx < 1056; kidx += 256) {
    int e;
    if (kidx < 225) {
      int t = kidx / 45, pos = kidx % 45;
      int y = wy * 5 + pos / 9, x = wx * 9 + pos % 9;
      e = (t * 60 + y) * 108 + x;
    } else if (kidx < 825) {
      int jj = kidx - 225;
      int t = jj / 120, m = jj % 120;
      int vir = VIR_TBL[m];
      int p = vir / 45, pos = vir % 45;
      int r = pos / 9, c = pos % 9;
      int sy = (p < 2) ? -2 : 2;
      int sx = (p & 1) ? 4 : -4;
      int y = (wy * 5 + r - sy + 60) % 60;
      int x = (wx * 9 + c - sx + 108) % 108;
      e = (t * 60 + y) * 108 + x;
    } else if (kidx < 1050) {
      int jp = kidx - 825;
      int t = jp / 45, pos = jp % 45;
      int py = wy + pos / 9 - 2;
      int px = wx + pos % 9 - 4;
      e = (py >= 0 && py < 12 && px >= 0 && px < 12)
            ? (PROW + t * 144 + py * 12 + px) : ZROW;
    } else {
      e = ZROW;
    }
    Tok[win * 1056 + kidx] = e;
  }
  if (threadIdx.x < 33) {
    int m = 0;
#pragma unroll 1
    for (int r = 0; r < 32; r++) {
      int kidx = threadIdx.x * 32 + r;
      bool v;
      if (kidx < 825) v = true;
      else if (kidx < 1050) {
        int jp = kidx - 825, pos = jp % 45;
        int py = wy + pos / 9 - 2, px = wx + pos % 9 - 4;
        v = (py >= 0 && py < 12 && px >= 0 && px < 12);
      } else v = false;
      m |= (v ? 1 : 0) << r;
    }
    WMask[win * 33 + threadIdx.x] = m;
  }
}

// ---------------- zero_rows: clear the unified-buffer zero rows ----------
__global__ __launch_bounds__(256) void zero_rows(h16* __restrict__ a,
                                                 h16* __restrict__ b) {
  for (int k = threadIdx.x; k < 512; k += 256) {
    a[(size_t)ZROW * CDIM + k] = (h16)0.f;
    b[(size_t)ZROW * CDIM + k] = (h16)0.f;
  }
}

// ------------- transpose_cvt: src R x C fp32 -> dst C x R f16 ------------
__global__ __launch_bounds__(256) void transpose_cvt(const float* __restrict__ src,
                                                     h16* __restrict__ dst,
                                                     int R, int C) {
  __shared__ float T[32][33];
  const int t = threadIdx.x;
  const int ct = blockIdx.x * 32;
  const int rt = blockIdx.y * 32;
  const int c = t & 31, r0 = (t >> 5) * 4;
#pragma unroll
  for (int i = 0; i < 4; i++)
    T[r0 + i][c] = src[(size_t)(rt + r0 + i) * C + ct + c];
  __syncthreads();
#pragma unroll
  for (int i = 0; i < 4; i++)
    dst[(size_t)(ct + r0 + i) * R + rt + c] = (h16)T[c][r0 + i];
}

// ------------- cvt_x0: fp32 (NTOK x 512) -> f16 --------------------------
__global__ __launch_bounds__(256) void cvt_x0(const float* __restrict__ src,
                                              h16* __restrict__ dst) {
  const int total = NTOK * CDIM / 8;
  for (int i = blockIdx.x * 256 + threadIdx.x; i < total; i += gridDim.x * 256) {
    const float4* s = (const float4*)(src + (size_t)i * 8);
    float4 f0 = s[0], f1 = s[1];
    half8 h;
    h[0] = (h16)f0.x; h[1] = (h16)f0.y; h[2] = (h16)f0.z; h[3] = (h16)f0.w;
    h[4] = (h16)f1.x; h[5] = (h16)f1.y; h[6] = (h16)f1.z; h[7] = (h16)f1.w;
    *(half8*)(dst + (size_t)i * 8) = h;
  }
}

// ------------ MFMA GEMM LDS shapes (double-buffered staging) -------------
// Tile rows are 32 h16 = 64B = 4 granules (16B each). Without swizzle the
// fragment ds_read_b128 has only 8 distinct (addr mod 128B) slots over 64
// lanes -> ~8-way bank conflict. Granule swizzle: phys p = g ^ ((row>>1)&3).
// global_load_lds writes LDS linearly, so the swizzle is applied by
// permuting the per-lane GLOBAL source granule (both-sides rule, m104/m173):
//   source granule for lane l = (l&3) ^ ((l>>3)&3)   [same for rows +16]
// and reading fragments at granule (quad ^ ((col>>1)&3)).
struct __align__(16) Stage2 { h16 Ah[2][128][32]; h16 Bh[2][128][32]; };  // 32 KB
union __align__(16) GemmLDSQ { Stage2 s; h16 Cs[128][136]; };             // 34.8 KB

// GEMM 1: Xh(f16) @ Wqkvt^T + b -> Q,K,V (f16). Bt layout [n][k].
// 2-phase pipeline: issue next tile's global_load_lds BEFORE computing the
// current tile. A-tail rows (>= NTOK) clamp gather source (stores masked).
__global__ __launch_bounds__(256) void gemm_qkv_mfma(
    const h16* __restrict__ A, const h16* __restrict__ Bt,
    const float* __restrict__ bias,
    h16* __restrict__ Q, h16* __restrict__ K, h16* __restrict__ V)
{
  __shared__ GemmLDSQ u;
  const int tid = threadIdx.x;
  const int lane = tid & 63, wv = tid >> 6;
  const int col = lane & 15, quad = lane >> 4;
  const int bn = blockIdx.x, bm = blockIdx.y;
  const int mo = (wv & 1) * 64, no = (wv >> 1) * 64;

  float4v acc[4][4];
#pragma unroll
  for (int i = 0; i < 4; i++)
#pragma unroll
    for (int j = 0; j < 4; j++) acc[i][j] = (float4v){0.f, 0.f, 0.f, 0.f};

  const int lrow = lane >> 2;
  const int lcol = (((lane & 3) ^ ((lane >> 3) & 3)) * 8);  // swizzled source granule
  const int arow = bm * 128 + wv * 32 + lrow;
  const int ar = arow < NTOK ? arow : (NTOK - 1);
  const int ar2 = (arow + 16) < NTOK ? (arow + 16) : (NTOK - 1);
  const h16* Ag  = A + (size_t)ar * 512 + lcol;
  const h16* Ag2 = A + (size_t)ar2 * 512 + lcol;
  const h16* Bg  = Bt + (size_t)(bn * 128 + wv * 32 + lrow) * 512 + lcol;

#define STAGE_G(buf, k0) do {                                              \
    su8* Al = (su8*)&u.s.Ah[buf][wv * 32][0];                              \
    su8* Bl = (su8*)&u.s.Bh[buf][wv * 32][0];                              \
    __builtin_amdgcn_global_load_lds((gu8*)(Ag + (k0)),            Al,        16, 0, 0); \
    __builtin_amdgcn_global_load_lds((gu8*)(Ag2 + (k0)),           Al + 1024, 16, 0, 0); \
    __builtin_amdgcn_global_load_lds((gu8*)(Bg + (k0)),            Bl,        16, 0, 0); \
    __builtin_amdgcn_global_load_lds((gu8*)(Bg + (k0) + 16 * 512), Bl + 1024, 16, 0, 0); \
  } while (0)

  const int fsw = (quad ^ ((col >> 1) & 3)) * 8;  // swizzled fragment granule
  STAGE_G(0, 0);
  __syncthreads();   // drains vmcnt: buf0 ready
  for (int kt = 0; kt < 16; kt++) {
    const int cur = kt & 1;
    if (kt + 1 < 16) STAGE_G(cur ^ 1, (kt + 1) * 32);   // in flight over compute

    half8 afr[4], bfr[4];
#pragma unroll
    for (int i = 0; i < 4; i++)
      afr[i] = *(const half8*)&u.s.Ah[cur][mo + i * 16 + col][fsw];
#pragma unroll
    for (int j = 0; j < 4; j++)
      bfr[j] = *(const half8*)&u.s.Bh[cur][no + j * 16 + col][fsw];
#pragma unroll
    for (int i = 0; i < 4; i++)
#pragma unroll
      for (int j = 0; j < 4; j++)
        acc[i][j] = __builtin_amdgcn_mfma_f32_16x16x32_f16(afr[i], bfr[j], acc[i][j], 0, 0, 0);
    __syncthreads();  // drains next-tile loads + this tile's lgkm
  }

  float bv[4];
#pragma unroll
  for (int j = 0; j < 4; j++) bv[j] = bias[bn * 128 + no + j * 16 + col];
#pragma unroll
  for (int i = 0; i < 4; i++)
#pragma unroll
    for (int j = 0; j < 4; j++)
#pragma unroll
      for (int r = 0; r < 4; r++)
        u.Cs[mo + i * 16 + quad * 4 + r][no + j * 16 + col] = (h16)(acc[i][j][r] + bv[j]);
  __syncthreads();

  const int row_l = tid >> 1, halfseg = (tid & 1) * 64;
  const int row_g = bm * 128 + row_l;
  const int jsel = bn >> 2;
  const int ch0 = (bn & 3) * 128 + halfseg;
  h16* dst = (jsel == 0) ? Q : (jsel == 1) ? K : V;
  if (row_g < NTOK) {
#pragma unroll
    for (int c = 0; c < 64; c += 8)
      *(half8*)&dst[(size_t)row_g * 512 + ch0 + c] = *(const half8*)&u.Cs[row_l][halfseg + c];
  }
}

// GEMM 3: AO(f16) @ Wprojt^T + b -> out (fp32). Same 2-phase + swizzle.
__global__ __launch_bounds__(256) void gemm_proj_mfma(
    const h16* __restrict__ A, const h16* __restrict__ Bt,
    const float* __restrict__ bias, float* __restrict__ out)
{
  __shared__ Stage2 s;
  const int tid = threadIdx.x;
  const int lane = tid & 63, wv = tid >> 6;
  const int col = lane & 15, quad = lane >> 4;
  const int bn = blockIdx.x, bm = blockIdx.y;
  const int mo = (wv & 1) * 64, no = (wv >> 1) * 64;

  float4v acc[4][4];
#pragma unroll
  for (int i = 0; i < 4; i++)
#pragma unroll
    for (int j = 0; j < 4; j++) acc[i][j] = (float4v){0.f, 0.f, 0.f, 0.f};

  const int lrow = lane >> 2;
  const int lcol = (((lane & 3) ^ ((lane >> 3) & 3)) * 8);
  const int arow = bm * 128 + wv * 32 + lrow;
  const int ar = arow < NTOK ? arow : (NTOK - 1);
  const int ar2 = (arow + 16) < NTOK ? (arow + 16) : (NTOK - 1);
  const h16* Ag  = A + (size_t)ar * 512 + lcol;
  const h16* Ag2 = A + (size_t)ar2 * 512 + lcol;
  const h16* Bg  = Bt + (size_t)(bn * 128 + wv * 32 + lrow) * 512 + lcol;

#define STAGE_P(buf, k0) do {                                              \
    su8* Al = (su8*)&s.Ah[buf][wv * 32][0];                                \
    su8* Bl = (su8*)&s.Bh[buf][wv * 32][0];                                \
    __builtin_amdgcn_global_load_lds((gu8*)(Ag + (k0)),            Al,        16, 0, 0); \
    __builtin_amdgcn_global_load_lds((gu8*)(Ag2 + (k0)),           Al + 1024, 16, 0, 0); \
    __builtin_amdgcn_global_load_lds((gu8*)(Bg + (k0)),            Bl,        16, 0, 0); \
    __builtin_amdgcn_global_load_lds((gu8*)(Bg + (k0) + 16 * 512), Bl + 1024, 16, 0, 0); \
  } while (0)

  const int fsw = (quad ^ ((col >> 1) & 3)) * 8;
  STAGE_P(0, 0);
  __syncthreads();
  for (int kt = 0; kt < 16; kt++) {
    const int cur = kt & 1;
    if (kt + 1 < 16) STAGE_P(cur ^ 1, (kt + 1) * 32);

    half8 afr[4], bfr[4];
#pragma unroll
    for (int i = 0; i < 4; i++)
      afr[i] = *(const half8*)&s.Ah[cur][mo + i * 16 + col][fsw];
#pragma unroll
    for (int j = 0; j < 4; j++)
      bfr[j] = *(const half8*)&s.Bh[cur][no + j * 16 + col][fsw];
#pragma unroll
    for (int i = 0; i < 4; i++)
#pragma unroll
      for (int j = 0; j < 4; j++)
        acc[i][j] = __builtin_amdgcn_mfma_f32_16x16x32_f16(afr[i], bfr[j], acc[i][j], 0, 0, 0);
    __syncthreads();
  }

  float bv[4];
#pragma unroll
  for (int j = 0; j < 4; j++) bv[j] = bias[bn * 128 + no + j * 16 + col];
#pragma unroll
  for (int i = 0; i < 4; i++) {
#pragma unroll
    for (int r = 0; r < 4; r++) {
      int row_g = bm * 128 + mo + i * 16 + quad * 4 + r;
      if (row_g < NTOK) {
#pragma unroll
        for (int j = 0; j < 4; j++)
          out[(size_t)row_g * 512 + bn * 128 + no + j * 16 + col] = acc[i][j][r] + bv[j];
      }
    }
  }
}

// ---------------- GEMM 2: pooled x1 @ W_qkv[:,512:] -> Kp,Vp -------------
__global__ __launch_bounds__(256) void gemm_pooled(
    const float* __restrict__ A, const float* __restrict__ B,
    const float* __restrict__ bias,
    h16* __restrict__ Kp, h16* __restrict__ Vp)
{
  __shared__ float As[64][17];
  __shared__ float Bs[16][64];
  const int tid = threadIdx.x;
  const int bm = blockIdx.x, bn = blockIdx.y;
  const int tm = tid >> 4, tn = tid & 15;
  const int lrow = tid >> 2, lk = (tid & 3) * 4;
  const int brow = tid >> 4, bcol = (tid & 15) * 4;
  float acc[4][4] = {};
  const int orow = bm * 64 + lrow;
  int srow = 0;
  if (orow < NPTOK) { int t = orow / 144, rem = orow % 144; srow = rem * 5 + t; }
  const float* Ap = A + (size_t)srow * 512 + lk;
  const float* Bp = B + (size_t)brow * 1536 + 512 + bn * 64 + bcol;

  for (int k0 = 0; k0 < 512; k0 += 16) {
    float4 av = make_float4(0.f, 0.f, 0.f, 0.f);
    if (orow < NPTOK) av = *(const float4*)(Ap + k0);
    float4 bv = *(const float4*)(Bp + (size_t)k0 * 1536);
    As[lrow][lk + 0] = av.x; As[lrow][lk + 1] = av.y;
    As[lrow][lk + 2] = av.z; As[lrow][lk + 3] = av.w;
    *(float4*)&Bs[brow][bcol] = bv;
    __syncthreads();
#pragma unroll
    for (int kk = 0; kk < 16; kk++) {
      float a[4];
#pragma unroll
      for (int i = 0; i < 4; i++) a[i] = As[tm * 4 + i][kk];
      float4 b = *(const float4*)&Bs[kk][tn * 4];
#pragma unroll
      for (int i = 0; i < 4; i++) {
        acc[i][0] = fmaf(a[i], b.x, acc[i][0]);
        acc[i][1] = fmaf(a[i], b.y, acc[i][1]);
        acc[i][2] = fmaf(a[i], b.z, acc[i][2]);
        acc[i][3] = fmaf(a[i], b.w, acc[i][3]);
      }
    }
    __syncthreads();
  }
  const int nl = bn * 64 + tn * 4;
  const int j = nl >> 9;
  const int ch = nl & 511;
  h16* dst = (j == 0) ? Kp : Vp;
#pragma unroll
  for (int i = 0; i < 4; i++) {
    int r = bm * 64 + tm * 4 + i;
    if (r < NPTOK) {
#pragma unroll
      for (int c = 0; c < 4; c++)
        dst[(size_t)r * 512 + ch + c] = (h16)(acc[i][c] + bias[512 + nl + c]);
    }
  }
}

// ---------------- Attention v7: v5 structure + K-tile XOR swizzle --------
// grid (144 win, 4 head, 2 qgroup), 256 thr / 4 waves (round-4 lesson: the
// 8-wave merge halved traffic but starved TLP -> slower; traffic was never
// the limiter). LDS double-buffer, 1 barrier/step; setprio around MFMA.
// NEW: Ks stride 136->128 h16 with granule swizzle p = g ^ (row&7): the old
// layout's S^T ds_read_b128 had only 8 distinct addr-mod-128B slots over 64
// lanes (~8-way conflict, matches the constant 2.92e7 SQ_LDS_BANK_CONFLICT);
// swizzled reads hit all 8 slots per 8-lane phase (write side swizzled
// identically -- register ds_write, so both sides are free to permute).
// launch_bounds(256,3): (256,4) caps VGPR at 64 < working set -> scratch
// spill catastrophe (round-2: 4.4x HBM fetch, 2.6x slowdown).
__global__ __launch_bounds__(256, 3) void attn_kernel(
    const h16* __restrict__ Qh, const h16* __restrict__ KhU,
    const h16* __restrict__ VhU, const int* __restrict__ Tok,
    const int* __restrict__ WMask, h16* __restrict__ AOh)
{
  __shared__ __align__(16) h16 Ks[2][32 * 128];
  __shared__ __align__(16) h16 Vt[2][128 * 40];

  const int tid = threadIdx.x;
  const int lane = tid & 63;
  const int wv = tid >> 6;
  const int win = blockIdx.x;
  const int head = blockIdx.y;
  const int qg = blockIdx.z;
  const int wy = win / 12, wx = win % 12;
  const int col = lane & 15;
  const int quad = lane >> 4;
  const int* TokW = Tok + win * 1056;
  const int* WMaskW = WMask + win * 33;

  // ---- Q fragments for 2 tiles ----
  half8 qfrag[2][4];
  const int tile0 = qg * 8 + wv * 2;
#pragma unroll
  for (int tt = 0; tt < 2; tt++) {
    int qrow = (tile0 + tt) * 16 + col;
    if (qrow < 225) {
      int t = qrow / 45, pos = qrow % 45;
      int y = wy * 5 + pos / 9, x = wx * 9 + pos % 9;
      const h16* qsrc = Qh + (size_t)((t * 60 + y) * 108 + x) * CDIM + head * 128;
#pragma unroll
      for (int dc = 0; dc < 4; dc++)
        qfrag[tt][dc] = *(const half8*)(qsrc + dc * 32 + quad * 8);
    } else {
#pragma unroll
      for (int dc = 0; dc < 4; dc++)
#pragma unroll
        for (int jj = 0; jj < 8; jj++) qfrag[tt][dc][jj] = (h16)0.f;
    }
  }

  float4v O[2][8];
#pragma unroll
  for (int tt = 0; tt < 2; tt++)
#pragma unroll
    for (int i = 0; i < 8; i++) O[tt][i] = (float4v){0.f, 0.f, 0.f, 0.f};
  float lp[2] = {0.f, 0.f};

  // staging roles
  const int krow = tid >> 3, kseg = tid & 7;
  const int vrp = tid >> 4, vcg = tid & 15;
  const int kch = head * 128 + kseg * 16;
  const int vch = head * 128 + vcg * 8;
  const int rp = (vrp + (vcg & 3) * 4) & 15;
  // swizzled K write granules (granule = 16B = 8 h16)
  const int kg0 = ((2 * kseg) ^ (krow & 7)) * 8;
  const int kg1 = ((2 * kseg + 1) ^ (krow & 7)) * 8;

  // ---- prologue: gather+stage step0 into buf0; gather step1 into regs ----
  {
    const h16* ks = KhU + (size_t)TokW[krow] * CDIM + kch;
    half8 k0c = *(const half8*)ks;
    half8 k1c = *(const half8*)(ks + 8);
    half8 vac = *(const half8*)(VhU + (size_t)TokW[2 * vrp] * CDIM + vch);
    half8 vbc = *(const half8*)(VhU + (size_t)TokW[2 * vrp + 1] * CDIM + vch);
    *(half8*)&Ks[0][krow * 128 + kg0] = k0c;
    *(half8*)&Ks[0][krow * 128 + kg1] = k1c;
#pragma unroll
    for (int i = 0; i < 8; i++) {
      half2v w; w[0] = vac[i]; w[1] = vbc[i];
      *(half2v*)&Vt[0][(vcg * 8 + i) * 40 + rp * 2] = w;
    }
  }
  half8 k0n, k1n, van, vbn;
  {
    const h16* ks = KhU + (size_t)TokW[32 + krow] * CDIM + kch;
    k0n = *(const half8*)ks;
    k1n = *(const half8*)(ks + 8);
    van = *(const half8*)(VhU + (size_t)TokW[32 + 2 * vrp] * CDIM + vch);
    vbn = *(const half8*)(VhU + (size_t)TokW[32 + 2 * vrp + 1] * CDIM + vch);
  }
  // token ring: slot (s&1) holds rows for step s+2 at the top of step s
  int tokK[2], tokVa[2], tokVb[2];
  tokK[0] = TokW[64 + krow]; tokVa[0] = TokW[64 + 2 * vrp]; tokVb[0] = TokW[64 + 2 * vrp + 1];
  tokK[1] = TokW[96 + krow]; tokVa[1] = TokW[96 + 2 * vrp]; tokVb[1] = TokW[96 + 2 * vrp + 1];
  __syncthreads();

  for (int step = 0; step < 33; ++step) {
    const int cur = step & 1;

    // ---- stage NEXT tile into the other buffer (overlaps compute) ----
    if (step + 1 < 33) {
      h16* KsN = Ks[cur ^ 1];
      h16* VtN = Vt[cur ^ 1];
      *(half8*)&KsN[krow * 128 + kg0] = k0n;
      *(half8*)&KsN[krow * 128 + kg1] = k1n;
#pragma unroll
      for (int i = 0; i < 8; i++) {
        half2v w; w[0] = van[i]; w[1] = vbn[i];
        *(half2v*)&VtN[(vcg * 8 + i) * 40 + rp * 2] = w;
      }
    }
    // ---- issue gathers for step+2 (latency hidden under compute) ----
    if (step + 2 < 33) {
      const h16* ks = KhU + (size_t)tokK[cur] * CDIM + kch;
      k0n = *(const half8*)ks;
      k1n = *(const half8*)(ks + 8);
      van = *(const half8*)(VhU + (size_t)tokVa[cur] * CDIM + vch);
      vbn = *(const half8*)(VhU + (size_t)tokVb[cur] * CDIM + vch);
      if (step + 4 < 33) {
        tokK[cur]  = TokW[(step + 4) * 32 + krow];
        tokVa[cur] = TokW[(step + 4) * 32 + 2 * vrp];
        tokVb[cur] = TokW[(step + 4) * 32 + 2 * vrp + 1];
      }
    }

    const int mask = WMaskW[step];
    const h16* KsC = Ks[cur];
    const h16* VtC = Vt[cur];

    // ---- S^T = K.Q^T (operand-swapped; swizzled K reads) ----
    float4v s0[2] = {{0.f,0.f,0.f,0.f},{0.f,0.f,0.f,0.f}};
    float4v s1[2] = {{0.f,0.f,0.f,0.f},{0.f,0.f,0.f,0.f}};
    __builtin_amdgcn_s_setprio(1);
#pragma unroll
    for (int dc = 0; dc < 4; dc++) {
      const int kg = ((dc * 4 + quad) ^ (col & 7)) * 8;   // (col+16)&7 == col&7
      half8 a0 = *(const half8*)&KsC[col * 128 + kg];
      half8 a1 = *(const half8*)&KsC[(col + 16) * 128 + kg];
#pragma unroll
      for (int tt = 0; tt < 2; tt++) {
        s0[tt] = __builtin_amdgcn_mfma_f32_16x16x32_f16(a0, qfrag[tt][dc], s0[tt], 0, 0, 0);
        s1[tt] = __builtin_amdgcn_mfma_f32_16x16x32_f16(a1, qfrag[tt][dc], s1[tt], 0, 0, 0);
      }
    }
    __builtin_amdgcn_s_setprio(0);

    // ---- fixed-max softmax + P^T -> A-frag via shuffles ----
    half8 pfrag[2];
    const int srcA = (((quad << 1) & 3) << 4) | col;
    const int srcB = ((((quad << 1) + 1) & 3) << 4) | col;
    const bool hi = quad >= 2;
#pragma unroll
    for (int tt = 0; tt < 2; tt++) {
      float pm0[4], pm1[4];
#pragma unroll
      for (int i = 0; i < 4; i++) {
        int r = quad * 4 + i;
        float e0 = __expf(s0[tt][i] * SCALE);
        float e1 = __expf(s1[tt][i] * SCALE);
        pm0[i] = ((mask >> r) & 1) ? e0 : 0.f;
        pm1[i] = ((mask >> (16 + r)) & 1) ? e1 : 0.f;
        lp[tt] += pm0[i] + pm1[i];
      }
      float g00 = __builtin_bit_cast(float, __builtin_amdgcn_cvt_pkrtz(pm0[0], pm0[1]));
      float g01 = __builtin_bit_cast(float, __builtin_amdgcn_cvt_pkrtz(pm0[2], pm0[3]));
      float g10 = __builtin_bit_cast(float, __builtin_amdgcn_cvt_pkrtz(pm1[0], pm1[1]));
      float g11 = __builtin_bit_cast(float, __builtin_amdgcn_cvt_pkrtz(pm1[2], pm1[3]));
      float a0 = __shfl(g00, srcA), a1 = __shfl(g01, srcA);
      float a2 = __shfl(g00, srcB), a3 = __shfl(g01, srcB);
      float b0 = __shfl(g10, srcA), b1 = __shfl(g11, srcA);
      float b2 = __shfl(g10, srcB), b3 = __shfl(g11, srcB);
      float4v pf;
      pf[0] = hi ? b0 : a0;
      pf[1] = hi ? b1 : a1;
      pf[2] = hi ? b2 : a2;
      pf[3] = hi ? b3 : a3;
      pfrag[tt] = __builtin_bit_cast(half8, pf);
    }

    // ---- O += P V (shared V fragments, single b128 each) ----
    __builtin_amdgcn_s_setprio(1);
#pragma unroll
    for (int dt = 0; dt < 8; dt++) {
      int ch = dt * 16 + col;
      int g4 = ((dt * 2 + (col >> 3)) & 3) * 4;
      int x0 = (quad * 4 + g4) & 15;
      half8 vf = *(const half8*)&VtC[ch * 40 + x0 * 2];
#pragma unroll
      for (int tt = 0; tt < 2; tt++)
        O[tt][dt] = __builtin_amdgcn_mfma_f32_16x16x32_f16(pfrag[tt], vf, O[tt][dt], 0, 0, 0);
    }
    __builtin_amdgcn_s_setprio(0);

    // single barrier: covers RAW on buf[cur^1] writes and WAR on buf[cur] reads
    __syncthreads();
  }

  // ---- epilogue: deferred l reduction + store ----
#pragma unroll
  for (int tt = 0; tt < 2; tt++) {
    float l_all = lp[tt];
    l_all += __shfl_xor(l_all, 16);
    l_all += __shfl_xor(l_all, 32);
#pragma unroll
    for (int i = 0; i < 4; i++) {
      int qr = (tile0 + tt) * 16 + quad * 4 + i;
      if (qr < 225) {
        float invl = __builtin_amdgcn_rcpf(__shfl(l_all, quad * 4 + i));
        h16* dst = AOh + ((size_t)win * 225 + qr) * CDIM + head * 128 + col;
#pragma unroll
        for (int dt = 0; dt < 8; dt++)
          dst[dt * 16] = (h16)(O[tt][dt][i] * invl);
      }
    }
  }
}

extern "C" void kernel_launch(void* const* d_in, const int* in_sizes, int n_in,
                              void* d_out, int out_size, void* d_ws, size_t ws_size,
                              hipStream_t stream) {
  const float* x0    = (const float*)d_in[0];
  const float* x1    = (const float*)d_in[1];
  const float* Wqkv  = (const float*)d_in[2];
  const float* bqkv  = (const float*)d_in[3];
  const float* Wproj = (const float*)d_in[4];
  const float* bproj = (const float*)d_in[5];
  float* out = (float*)d_out;

  const size_t NU = (size_t)(NTOK + 1 + NPTOK);   // unified K/V row count
  h16* Qh   = (h16*)d_ws;
  h16* KhU  = Qh + (size_t)NTOK * CDIM;
  h16* VhU  = KhU + NU * CDIM;
  // Rh: NTOK x 512 f16 region, time-shared: x0h (GEMM1 input) then AOh
  h16* Rh   = VhU + NU * CDIM;
  h16* Wqkvt  = Rh + (size_t)NTOK * CDIM;         // 1536 x 512
  h16* Wprojt = Wqkvt + (size_t)1536 * 512;       // 512 x 512
  int* Tok    = (int*)(Wprojt + (size_t)512 * 512);  // 144 x 1056
  int* WMaskP = Tok + (size_t)144 * 1056;            // 144 x 33

  build_tok<<<144, 256, 0, stream>>>(Tok, WMaskP);
  zero_rows<<<1, 256, 0, stream>>>(KhU, VhU);
  transpose_cvt<<<dim3(48, 16), 256, 0, stream>>>(Wqkv, Wqkvt, 512, 1536);
  transpose_cvt<<<dim3(16, 16), 256, 0, stream>>>(Wproj, Wprojt, 512, 512);
  cvt_x0<<<2048, 256, 0, stream>>>(x0, Rh);

  gemm_qkv_mfma<<<dim3(12, 254), 256, 0, stream>>>(Rh, Wqkvt, bqkv, Qh, KhU, VhU);
  gemm_pooled<<<dim3(12, 16), 256, 0, stream>>>(x1, Wqkv, bqkv,
                                                KhU + (size_t)PROW * CDIM,
                                                VhU + (size_t)PROW * CDIM);
  attn_kernel<<<dim3(144, 4, 2), 256, 0, stream>>>(Qh, KhU, VhU, Tok, WMaskP, Rh);
  gemm_proj_mfma<<<dim3(4, 254), 256, 0, stream>>>(Rh, Wprojt, bproj, out);
}

// Round 6
// 452.092 us; speedup vs baseline: 1.0806x; 1.0339x over previous
//
#include <hip/hip_runtime.h>

typedef _Float16 h16;
typedef __attribute__((ext_vector_type(8))) _Float16 half8;
typedef __attribute__((ext_vector_type(2))) _Float16 half2v;
typedef __attribute__((ext_vector_type(4))) float float4v;

typedef const __attribute__((address_space(1))) unsigned char gu8;
typedef __attribute__((address_space(3))) unsigned char su8;

#define NTOK  32400   // 5*60*108
#define NPTOK 720     // 5*12*12
#define CDIM  512
#define SCALE 0.08838834764831845f
#define ZROW  NTOK            // zero row index in unified K/V buffers
#define PROW  (NTOK + 1)      // pooled rows start

// valid-index table for the rolled halo (nonzero of stacked tl,tr,bl,br 5x9 masks)
__constant__ int VIR_TBL[120] = {
  5,6,7,8, 14,15,16,17, 23,24,25,26,
  27,28,29,30,31,32,33,34,35, 36,37,38,39,40,41,42,43,44,
  45,46,47,48, 54,55,56,57, 63,64,65,66,
  72,73,74,75,76,77,78,79,80, 81,82,83,84,85,86,87,88,89,
  90,91,92,93,94,95,96,97,98, 99,100,101,102,103,104,105,106,107,
  113,114,115,116, 122,123,124,125, 131,132,133,134,
  135,136,137,138,139,140,141,142,143, 144,145,146,147,148,149,150,151,152,
  153,154,155,156, 162,163,164,165, 171,172,173,174
};

// ---------------- token row table + per-step valid mask -------------------
// (zero_rows folded into block 0 to save one launch)
__global__ __launch_bounds__(256) void build_tok(int* __restrict__ Tok,
                                                 int* __restrict__ WMask,
                                                 h16* __restrict__ Kz,
                                                 h16* __restrict__ Vz) {
  const int win = blockIdx.x;
  const int wy = win / 12, wx = win % 12;
  if (win == 0) {
    for (int k = threadIdx.x; k < 512; k += 256) {
      Kz[(size_t)ZROW * CDIM + k] = (h16)0.f;
      Vz[(size_t)ZROW * CDIM + k] = (h16)0.f;
    }
  }
  for (int kidx = threadIdx.x; kidx < 1056; kidx += 256) {
    int e;
    if (kidx < 225) {
      int t = kidx / 45, pos = kidx % 45;
      int y = wy * 5 + pos / 9, x = wx * 9 + pos % 9;
      e = (t * 60 + y) * 108 + x;
    } else if (kidx < 825) {
      int jj = kidx - 225;
      int t = jj / 120, m = jj % 120;
      int vir = VIR_TBL[m];
      int p = vir / 45, pos = vir % 45;
      int r = pos / 9, c = pos % 9;
      int sy = (p < 2) ? -2 : 2;
      int sx = (p & 1) ? 4 : -4;
      int y = (wy * 5 + r - sy + 60) % 60;
      int x = (wx * 9 + c - sx + 108) % 108;
      e = (t * 60 + y) * 108 + x;
    } else if (kidx < 1050) {
      int jp = kidx - 825;
      int t = jp / 45, pos = jp % 45;
      int py = wy + pos / 9 - 2;
      int px = wx + pos % 9 - 4;
      e = (py >= 0 && py < 12 && px >= 0 && px < 12)
            ? (PROW + t * 144 + py * 12 + px) : ZROW;
    } else {
      e = ZROW;
    }
    Tok[win * 1056 + kidx] = e;
  }
  if (threadIdx.x < 33) {
    int m = 0;
#pragma unroll 1
    for (int r = 0; r < 32; r++) {
      int kidx = threadIdx.x * 32 + r;
      bool v;
      if (kidx < 825) v = true;
      else if (kidx < 1050) {
        int jp = kidx - 825, pos = jp % 45;
        int py = wy + pos / 9 - 2, px = wx + pos % 9 - 4;
        v = (py >= 0 && py < 12 && px >= 0 && px < 12);
      } else v = false;
      m |= (v ? 1 : 0) << r;
    }
    WMask[win * 33 + threadIdx.x] = m;
  }
}

// ------------- transpose_cvt: src R x C fp32 -> dst C x R f16 ------------
__global__ __launch_bounds__(256) void transpose_cvt(const float* __restrict__ src,
                                                     h16* __restrict__ dst,
                                                     int R, int C) {
  __shared__ float T[32][33];
  const int t = threadIdx.x;
  const int ct = blockIdx.x * 32;
  const int rt = blockIdx.y * 32;
  const int c = t & 31, r0 = (t >> 5) * 4;
#pragma unroll
  for (int i = 0; i < 4; i++)
    T[r0 + i][c] = src[(size_t)(rt + r0 + i) * C + ct + c];
  __syncthreads();
#pragma unroll
  for (int i = 0; i < 4; i++)
    dst[(size_t)(ct + r0 + i) * R + rt + c] = (h16)T[c][r0 + i];
}

// ------------- cvt_x0: fp32 (NTOK x 512) -> f16 --------------------------
__global__ __launch_bounds__(256) void cvt_x0(const float* __restrict__ src,
                                              h16* __restrict__ dst) {
  const int total = NTOK * CDIM / 8;
  for (int i = blockIdx.x * 256 + threadIdx.x; i < total; i += gridDim.x * 256) {
    const float4* s = (const float4*)(src + (size_t)i * 8);
    float4 f0 = s[0], f1 = s[1];
    half8 h;
    h[0] = (h16)f0.x; h[1] = (h16)f0.y; h[2] = (h16)f0.z; h[3] = (h16)f0.w;
    h[4] = (h16)f1.x; h[5] = (h16)f1.y; h[6] = (h16)f1.z; h[7] = (h16)f1.w;
    *(half8*)(dst + (size_t)i * 8) = h;
  }
}

// ------------ MFMA GEMM LDS shapes (double-buffered staging) -------------
// Tile rows are 32 h16 = 64B = 4 granules (16B each). Granule swizzle
// p = g ^ ((row>>1)&3) kills the 8-way fragment-read conflict; since
// global_load_lds writes LDS linearly, the swizzle is applied by permuting
// the per-lane GLOBAL source granule (both-sides rule):
//   source granule for lane l = (l&3) ^ ((l>>3)&3)
// and reading fragments at granule (quad ^ ((col>>1)&3)).
// Measured (r4->r5): 2-phase pipeline -6us, +swizzle -19us on the GEMM chain.
struct __align__(16) Stage2 { h16 Ah[2][128][32]; h16 Bh[2][128][32]; };  // 32 KB
union __align__(16) GemmLDSQ { Stage2 s; h16 Cs[128][136]; };             // 34.8 KB

// GEMM 1: Xh(f16) @ Wqkvt^T + b -> Q,K,V (f16). Bt layout [n][k].
__global__ __launch_bounds__(256) void gemm_qkv_mfma(
    const h16* __restrict__ A, const h16* __restrict__ Bt,
    const float* __restrict__ bias,
    h16* __restrict__ Q, h16* __restrict__ K, h16* __restrict__ V)
{
  __shared__ GemmLDSQ u;
  const int tid = threadIdx.x;
  const int lane = tid & 63, wv = tid >> 6;
  const int col = lane & 15, quad = lane >> 4;
  const int bn = blockIdx.x, bm = blockIdx.y;
  const int mo = (wv & 1) * 64, no = (wv >> 1) * 64;

  float4v acc[4][4];
#pragma unroll
  for (int i = 0; i < 4; i++)
#pragma unroll
    for (int j = 0; j < 4; j++) acc[i][j] = (float4v){0.f, 0.f, 0.f, 0.f};

  const int lrow = lane >> 2;
  const int lcol = (((lane & 3) ^ ((lane >> 3) & 3)) * 8);  // swizzled source granule
  const int arow = bm * 128 + wv * 32 + lrow;
  const int ar = arow < NTOK ? arow : (NTOK - 1);
  const int ar2 = (arow + 16) < NTOK ? (arow + 16) : (NTOK - 1);
  const h16* Ag  = A + (size_t)ar * 512 + lcol;
  const h16* Ag2 = A + (size_t)ar2 * 512 + lcol;
  const h16* Bg  = Bt + (size_t)(bn * 128 + wv * 32 + lrow) * 512 + lcol;

#define STAGE_G(buf, k0) do {                                              \
    su8* Al = (su8*)&u.s.Ah[buf][wv * 32][0];                              \
    su8* Bl = (su8*)&u.s.Bh[buf][wv * 32][0];                              \
    __builtin_amdgcn_global_load_lds((gu8*)(Ag + (k0)),            Al,        16, 0, 0); \
    __builtin_amdgcn_global_load_lds((gu8*)(Ag2 + (k0)),           Al + 1024, 16, 0, 0); \
    __builtin_amdgcn_global_load_lds((gu8*)(Bg + (k0)),            Bl,        16, 0, 0); \
    __builtin_amdgcn_global_load_lds((gu8*)(Bg + (k0) + 16 * 512), Bl + 1024, 16, 0, 0); \
  } while (0)

  const int fsw = (quad ^ ((col >> 1) & 3)) * 8;  // swizzled fragment granule
  STAGE_G(0, 0);
  __syncthreads();   // drains vmcnt: buf0 ready
  for (int kt = 0; kt < 16; kt++) {
    const int cur = kt & 1;
    if (kt + 1 < 16) STAGE_G(cur ^ 1, (kt + 1) * 32);   // in flight over compute

    half8 afr[4], bfr[4];
#pragma unroll
    for (int i = 0; i < 4; i++)
      afr[i] = *(const half8*)&u.s.Ah[cur][mo + i * 16 + col][fsw];
#pragma unroll
    for (int j = 0; j < 4; j++)
      bfr[j] = *(const half8*)&u.s.Bh[cur][no + j * 16 + col][fsw];
#pragma unroll
    for (int i = 0; i < 4; i++)
#pragma unroll
      for (int j = 0; j < 4; j++)
        acc[i][j] = __builtin_amdgcn_mfma_f32_16x16x32_f16(afr[i], bfr[j], acc[i][j], 0, 0, 0);
    __syncthreads();  // drains next-tile loads + this tile's lgkm
  }

  float bv[4];
#pragma unroll
  for (int j = 0; j < 4; j++) bv[j] = bias[bn * 128 + no + j * 16 + col];
#pragma unroll
  for (int i = 0; i < 4; i++)
#pragma unroll
    for (int j = 0; j < 4; j++)
#pragma unroll
      for (int r = 0; r < 4; r++)
        u.Cs[mo + i * 16 + quad * 4 + r][no + j * 16 + col] = (h16)(acc[i][j][r] + bv[j]);
  __syncthreads();

  const int row_l = tid >> 1, halfseg = (tid & 1) * 64;
  const int row_g = bm * 128 + row_l;
  const int jsel = bn >> 2;
  const int ch0 = (bn & 3) * 128 + halfseg;
  h16* dst = (jsel == 0) ? Q : (jsel == 1) ? K : V;
  if (row_g < NTOK) {
#pragma unroll
    for (int c = 0; c < 64; c += 8)
      *(half8*)&dst[(size_t)row_g * 512 + ch0 + c] = *(const half8*)&u.Cs[row_l][halfseg + c];
  }
}

// GEMM 3: AO(f16) @ Wprojt^T + b -> out (fp32). Same 2-phase + swizzle.
__global__ __launch_bounds__(256) void gemm_proj_mfma(
    const h16* __restrict__ A, const h16* __restrict__ Bt,
    const float* __restrict__ bias, float* __restrict__ out)
{
  __shared__ Stage2 s;
  const int tid = threadIdx.x;
  const int lane = tid & 63, wv = tid >> 6;
  const int col = lane & 15, quad = lane >> 4;
  const int bn = blockIdx.x, bm = blockIdx.y;
  const int mo = (wv & 1) * 64, no = (wv >> 1) * 64;

  float4v acc[4][4];
#pragma unroll
  for (int i = 0; i < 4; i++)
#pragma unroll
    for (int j = 0; j < 4; j++) acc[i][j] = (float4v){0.f, 0.f, 0.f, 0.f};

  const int lrow = lane >> 2;
  const int lcol = (((lane & 3) ^ ((lane >> 3) & 3)) * 8);
  const int arow = bm * 128 + wv * 32 + lrow;
  const int ar = arow < NTOK ? arow : (NTOK - 1);
  const int ar2 = (arow + 16) < NTOK ? (arow + 16) : (NTOK - 1);
  const h16* Ag  = A + (size_t)ar * 512 + lcol;
  const h16* Ag2 = A + (size_t)ar2 * 512 + lcol;
  const h16* Bg  = Bt + (size_t)(bn * 128 + wv * 32 + lrow) * 512 + lcol;

#define STAGE_P(buf, k0) do {                                              \
    su8* Al = (su8*)&s.Ah[buf][wv * 32][0];                                \
    su8* Bl = (su8*)&s.Bh[buf][wv * 32][0];                                \
    __builtin_amdgcn_global_load_lds((gu8*)(Ag + (k0)),            Al,        16, 0, 0); \
    __builtin_amdgcn_global_load_lds((gu8*)(Ag2 + (k0)),           Al + 1024, 16, 0, 0); \
    __builtin_amdgcn_global_load_lds((gu8*)(Bg + (k0)),            Bl,        16, 0, 0); \
    __builtin_amdgcn_global_load_lds((gu8*)(Bg + (k0) + 16 * 512), Bl + 1024, 16, 0, 0); \
  } while (0)

  const int fsw = (quad ^ ((col >> 1) & 3)) * 8;
  STAGE_P(0, 0);
  __syncthreads();
  for (int kt = 0; kt < 16; kt++) {
    const int cur = kt & 1;
    if (kt + 1 < 16) STAGE_P(cur ^ 1, (kt + 1) * 32);

    half8 afr[4], bfr[4];
#pragma unroll
    for (int i = 0; i < 4; i++)
      afr[i] = *(const half8*)&s.Ah[cur][mo + i * 16 + col][fsw];
#pragma unroll
    for (int j = 0; j < 4; j++)
      bfr[j] = *(const half8*)&s.Bh[cur][no + j * 16 + col][fsw];
#pragma unroll
    for (int i = 0; i < 4; i++)
#pragma unroll
      for (int j = 0; j < 4; j++)
        acc[i][j] = __builtin_amdgcn_mfma_f32_16x16x32_f16(afr[i], bfr[j], acc[i][j], 0, 0, 0);
    __syncthreads();
  }

  float bv[4];
#pragma unroll
  for (int j = 0; j < 4; j++) bv[j] = bias[bn * 128 + no + j * 16 + col];
#pragma unroll
  for (int i = 0; i < 4; i++) {
#pragma unroll
    for (int r = 0; r < 4; r++) {
      int row_g = bm * 128 + mo + i * 16 + quad * 4 + r;
      if (row_g < NTOK) {
#pragma unroll
        for (int j = 0; j < 4; j++)
          out[(size_t)row_g * 512 + bn * 128 + no + j * 16 + col] = acc[i][j][r] + bv[j];
      }
    }
  }
}

// ---------------- GEMM 2: pooled x1 @ W_qkv[:,512:] -> Kp,Vp -------------
__global__ __launch_bounds__(256) void gemm_pooled(
    const float* __restrict__ A, const float* __restrict__ B,
    const float* __restrict__ bias,
    h16* __restrict__ Kp, h16* __restrict__ Vp)
{
  __shared__ float As[64][17];
  __shared__ float Bs[16][64];
  const int tid = threadIdx.x;
  const int bm = blockIdx.x, bn = blockIdx.y;
  const int tm = tid >> 4, tn = tid & 15;
  const int lrow = tid >> 2, lk = (tid & 3) * 4;
  const int brow = tid >> 4, bcol = (tid & 15) * 4;
  float acc[4][4] = {};
  const int orow = bm * 64 + lrow;
  int srow = 0;
  if (orow < NPTOK) { int t = orow / 144, rem = orow % 144; srow = rem * 5 + t; }
  const float* Ap = A + (size_t)srow * 512 + lk;
  const float* Bp = B + (size_t)brow * 1536 + 512 + bn * 64 + bcol;

  for (int k0 = 0; k0 < 512; k0 += 16) {
    float4 av = make_float4(0.f, 0.f, 0.f, 0.f);
    if (orow < NPTOK) av = *(const float4*)(Ap + k0);
    float4 bv = *(const float4*)(Bp + (size_t)k0 * 1536);
    As[lrow][lk + 0] = av.x; As[lrow][lk + 1] = av.y;
    As[lrow][lk + 2] = av.z; As[lrow][lk + 3] = av.w;
    *(float4*)&Bs[brow][bcol] = bv;
    __syncthreads();
#pragma unroll
    for (int kk = 0; kk < 16; kk++) {
      float a[4];
#pragma unroll
      for (int i = 0; i < 4; i++) a[i] = As[tm * 4 + i][kk];
      float4 b = *(const float4*)&Bs[kk][tn * 4];
#pragma unroll
      for (int i = 0; i < 4; i++) {
        acc[i][0] = fmaf(a[i], b.x, acc[i][0]);
        acc[i][1] = fmaf(a[i], b.y, acc[i][1]);
        acc[i][2] = fmaf(a[i], b.z, acc[i][2]);
        acc[i][3] = fmaf(a[i], b.w, acc[i][3]);
      }
    }
    __syncthreads();
  }
  const int nl = bn * 64 + tn * 4;
  const int j = nl >> 9;
  const int ch = nl & 511;
  h16* dst = (j == 0) ? Kp : Vp;
#pragma unroll
  for (int i = 0; i < 4; i++) {
    int r = bm * 64 + tm * 4 + i;
    if (r < NPTOK) {
#pragma unroll
      for (int c = 0; c < 4; c++)
        dst[(size_t)r * 512 + ch + c] = (h16)(acc[i][c] + bias[512 + nl + c]);
    }
  }
}

// ---------------- Attention (round-3 best: 171us) ------------------------
// grid (144 win, 4 head, 2 qgroup), 256 thr / 4 waves; wave owns 2 q-tiles.
// S^T = K.Q^T operand-swapped MFMA; fixed-max softmax; P^T->A-frag via 8
// packed shuffles. LDS double-buffer, 1 barrier/step; setprio around MFMA.
// Ks stride 136 h16 (=272B, odd dword multiple): natural bank spreading for
// the S^T b128 reads -- round-5 measured that a 128-stride+XOR "fix" left
// SQ_LDS_BANK_CONFLICT EXACTLY unchanged and cost 20% (extra index VALU),
// i.e. these reads were never the conflict source. Do not re-touch.
// launch_bounds(256,3): (256,4) caps VGPR at 64 < working set -> scratch
// spill catastrophe (round-2: 4.4x HBM fetch, 2.6x slowdown).
// 8-wave/512-thr merge (round-4): halves gather traffic but starves TLP,
// net -17%. Traffic is not the limiter; latency is. Do not re-merge.
__global__ __launch_bounds__(256, 3) void attn_kernel(
    const h16* __restrict__ Qh, const h16* __restrict__ KhU,
    const h16* __restrict__ VhU, const int* __restrict__ Tok,
    const int* __restrict__ WMask, h16* __restrict__ AOh)
{
  __shared__ __align__(16) h16 Ks[2][32 * 136];
  __shared__ __align__(16) h16 Vt[2][128 * 40];

  const int tid = threadIdx.x;
  const int lane = tid & 63;
  const int wv = tid >> 6;
  const int win = blockIdx.x;
  const int head = blockIdx.y;
  const int qg = blockIdx.z;
  const int wy = win / 12, wx = win % 12;
  const int col = lane & 15;
  const int quad = lane >> 4;
  const int* TokW = Tok + win * 1056;
  const int* WMaskW = WMask + win * 33;

  // ---- Q fragments for 2 tiles ----
  half8 qfrag[2][4];
  const int tile0 = qg * 8 + wv * 2;
#pragma unroll
  for (int tt = 0; tt < 2; tt++) {
    int qrow = (tile0 + tt) * 16 + col;
    if (qrow < 225) {
      int t = qrow / 45, pos = qrow % 45;
      int y = wy * 5 + pos / 9, x = wx * 9 + pos % 9;
      const h16* qsrc = Qh + (size_t)((t * 60 + y) * 108 + x) * CDIM + head * 128;
#pragma unroll
      for (int dc = 0; dc < 4; dc++)
        qfrag[tt][dc] = *(const half8*)(qsrc + dc * 32 + quad * 8);
    } else {
#pragma unroll
      for (int dc = 0; dc < 4; dc++)
#pragma unroll
        for (int jj = 0; jj < 8; jj++) qfrag[tt][dc][jj] = (h16)0.f;
    }
  }

  float4v O[2][8];
#pragma unroll
  for (int tt = 0; tt < 2; tt++)
#pragma unroll
    for (int i = 0; i < 8; i++) O[tt][i] = (float4v){0.f, 0.f, 0.f, 0.f};
  float lp[2] = {0.f, 0.f};

  // staging roles
  const int krow = tid >> 3, kseg = tid & 7;
  const int vrp = tid >> 4, vcg = tid & 15;
  const int kch = head * 128 + kseg * 16;
  const int vch = head * 128 + vcg * 8;
  const int rp = (vrp + (vcg & 3) * 4) & 15;

  // ---- prologue: gather+stage step0 into buf0; gather step1 into regs ----
  {
    const h16* ks = KhU + (size_t)TokW[krow] * CDIM + kch;
    half8 k0c = *(const half8*)ks;
    half8 k1c = *(const half8*)(ks + 8);
    half8 vac = *(const half8*)(VhU + (size_t)TokW[2 * vrp] * CDIM + vch);
    half8 vbc = *(const half8*)(VhU + (size_t)TokW[2 * vrp + 1] * CDIM + vch);
    *(half8*)&Ks[0][krow * 136 + kseg * 16] = k0c;
    *(half8*)&Ks[0][krow * 136 + kseg * 16 + 8] = k1c;
#pragma unroll
    for (int i = 0; i < 8; i++) {
      half2v w; w[0] = vac[i]; w[1] = vbc[i];
      *(half2v*)&Vt[0][(vcg * 8 + i) * 40 + rp * 2] = w;
    }
  }
  half8 k0n, k1n, van, vbn;
  {
    const h16* ks = KhU + (size_t)TokW[32 + krow] * CDIM + kch;
    k0n = *(const half8*)ks;
    k1n = *(const half8*)(ks + 8);
    van = *(const half8*)(VhU + (size_t)TokW[32 + 2 * vrp] * CDIM + vch);
    vbn = *(const half8*)(VhU + (size_t)TokW[32 + 2 * vrp + 1] * CDIM + vch);
  }
  // token ring: slot (s&1) holds rows for step s+2 at the top of step s
  int tokK[2], tokVa[2], tokVb[2];
  tokK[0] = TokW[64 + krow]; tokVa[0] = TokW[64 + 2 * vrp]; tokVb[0] = TokW[64 + 2 * vrp + 1];
  tokK[1] = TokW[96 + krow]; tokVa[1] = TokW[96 + 2 * vrp]; tokVb[1] = TokW[96 + 2 * vrp + 1];
  __syncthreads();

  for (int step = 0; step < 33; ++step) {
    const int cur = step & 1;

    // ---- stage NEXT tile into the other buffer (overlaps compute) ----
    if (step + 1 < 33) {
      h16* KsN = Ks[cur ^ 1];
      h16* VtN = Vt[cur ^ 1];
      *(half8*)&KsN[krow * 136 + kseg * 16] = k0n;
      *(half8*)&KsN[krow * 136 + kseg * 16 + 8] = k1n;
#pragma unroll
      for (int i = 0; i < 8; i++) {
        half2v w; w[0] = van[i]; w[1] = vbn[i];
        *(half2v*)&VtN[(vcg * 8 + i) * 40 + rp * 2] = w;
      }
    }
    // ---- issue gathers for step+2 (latency hidden under compute) ----
    if (step + 2 < 33) {
      const h16* ks = KhU + (size_t)tokK[cur] * CDIM + kch;
      k0n = *(const half8*)ks;
      k1n = *(const half8*)(ks + 8);
      van = *(const half8*)(VhU + (size_t)tokVa[cur] * CDIM + vch);
      vbn = *(const half8*)(VhU + (size_t)tokVb[cur] * CDIM + vch);
      if (step + 4 < 33) {
        tokK[cur]  = TokW[(step + 4) * 32 + krow];
        tokVa[cur] = TokW[(step + 4) * 32 + 2 * vrp];
        tokVb[cur] = TokW[(step + 4) * 32 + 2 * vrp + 1];
      }
    }

    const int mask = WMaskW[step];
    const h16* KsC = Ks[cur];
    const h16* VtC = Vt[cur];

    // ---- S^T = K.Q^T (operand-swapped) ----
    float4v s0[2] = {{0.f,0.f,0.f,0.f},{0.f,0.f,0.f,0.f}};
    float4v s1[2] = {{0.f,0.f,0.f,0.f},{0.f,0.f,0.f,0.f}};
    __builtin_amdgcn_s_setprio(1);
#pragma unroll
    for (int dc = 0; dc < 4; dc++) {
      half8 a0 = *(const half8*)&KsC[col * 136 + dc * 32 + quad * 8];
      half8 a1 = *(const half8*)&KsC[(col + 16) * 136 + dc * 32 + quad * 8];
#pragma unroll
      for (int tt = 0; tt < 2; tt++) {
        s0[tt] = __builtin_amdgcn_mfma_f32_16x16x32_f16(a0, qfrag[tt][dc], s0[tt], 0, 0, 0);
        s1[tt] = __builtin_amdgcn_mfma_f32_16x16x32_f16(a1, qfrag[tt][dc], s1[tt], 0, 0, 0);
      }
    }
    __builtin_amdgcn_s_setprio(0);

    // ---- fixed-max softmax + P^T -> A-frag via shuffles ----
    half8 pfrag[2];
    const int srcA = (((quad << 1) & 3) << 4) | col;
    const int srcB = ((((quad << 1) + 1) & 3) << 4) | col;
    const bool hi = quad >= 2;
#pragma unroll
    for (int tt = 0; tt < 2; tt++) {
      float pm0[4], pm1[4];
#pragma unroll
      for (int i = 0; i < 4; i++) {
        int r = quad * 4 + i;
        float e0 = __expf(s0[tt][i] * SCALE);
        float e1 = __expf(s1[tt][i] * SCALE);
        pm0[i] = ((mask >> r) & 1) ? e0 : 0.f;
        pm1[i] = ((mask >> (16 + r)) & 1) ? e1 : 0.f;
        lp[tt] += pm0[i] + pm1[i];
      }
      float g00 = __builtin_bit_cast(float, __builtin_amdgcn_cvt_pkrtz(pm0[0], pm0[1]));
      float g01 = __builtin_bit_cast(float, __builtin_amdgcn_cvt_pkrtz(pm0[2], pm0[3]));
      float g10 = __builtin_bit_cast(float, __builtin_amdgcn_cvt_pkrtz(pm1[0], pm1[1]));
      float g11 = __builtin_bit_cast(float, __builtin_amdgcn_cvt_pkrtz(pm1[2], pm1[3]));
      float a0 = __shfl(g00, srcA), a1 = __shfl(g01, srcA);
      float a2 = __shfl(g00, srcB), a3 = __shfl(g01, srcB);
      float b0 = __shfl(g10, srcA), b1 = __shfl(g11, srcA);
      float b2 = __shfl(g10, srcB), b3 = __shfl(g11, srcB);
      float4v pf;
      pf[0] = hi ? b0 : a0;
      pf[1] = hi ? b1 : a1;
      pf[2] = hi ? b2 : a2;
      pf[3] = hi ? b3 : a3;
      pfrag[tt] = __builtin_bit_cast(half8, pf);
    }

    // ---- O += P V (shared V fragments, single b128 each) ----
    __builtin_amdgcn_s_setprio(1);
#pragma unroll
    for (int dt = 0; dt < 8; dt++) {
      int ch = dt * 16 + col;
      int g4 = ((dt * 2 + (col >> 3)) & 3) * 4;
      int x0 = (quad * 4 + g4) & 15;
      half8 vf = *(const half8*)&VtC[ch * 40 + x0 * 2];
#pragma unroll
      for (int tt = 0; tt < 2; tt++)
        O[tt][dt] = __builtin_amdgcn_mfma_f32_16x16x32_f16(pfrag[tt], vf, O[tt][dt], 0, 0, 0);
    }
    __builtin_amdgcn_s_setprio(0);

    // single barrier: covers RAW on buf[cur^1] writes and WAR on buf[cur] reads
    __syncthreads();
  }

  // ---- epilogue: deferred l reduction + store ----
#pragma unroll
  for (int tt = 0; tt < 2; tt++) {
    float l_all = lp[tt];
    l_all += __shfl_xor(l_all, 16);
    l_all += __shfl_xor(l_all, 32);
#pragma unroll
    for (int i = 0; i < 4; i++) {
      int qr = (tile0 + tt) * 16 + quad * 4 + i;
      if (qr < 225) {
        float invl = __builtin_amdgcn_rcpf(__shfl(l_all, quad * 4 + i));
        h16* dst = AOh + ((size_t)win * 225 + qr) * CDIM + head * 128 + col;
#pragma unroll
        for (int dt = 0; dt < 8; dt++)
          dst[dt * 16] = (h16)(O[tt][dt][i] * invl);
      }
    }
  }
}

extern "C" void kernel_launch(void* const* d_in, const int* in_sizes, int n_in,
                              void* d_out, int out_size, void* d_ws, size_t ws_size,
                              hipStream_t stream) {
  const float* x0    = (const float*)d_in[0];
  const float* x1    = (const float*)d_in[1];
  const float* Wqkv  = (const float*)d_in[2];
  const float* bqkv  = (const float*)d_in[3];
  const float* Wproj = (const float*)d_in[4];
  const float* bproj = (const float*)d_in[5];
  float* out = (float*)d_out;

  const size_t NU = (size_t)(NTOK + 1 + NPTOK);   // unified K/V row count
  h16* Qh   = (h16*)d_ws;
  h16* KhU  = Qh + (size_t)NTOK * CDIM;
  h16* VhU  = KhU + NU * CDIM;
  // Rh: NTOK x 512 f16 region, time-shared: x0h (GEMM1 input) then AOh
  h16* Rh   = VhU + NU * CDIM;
  h16* Wqkvt  = Rh + (size_t)NTOK * CDIM;         // 1536 x 512
  h16* Wprojt = Wqkvt + (size_t)1536 * 512;       // 512 x 512
  int* Tok    = (int*)(Wprojt + (size_t)512 * 512);  // 144 x 1056
  int* WMaskP = Tok + (size_t)144 * 1056;            // 144 x 33

  build_tok<<<144, 256, 0, stream>>>(Tok, WMaskP, KhU, VhU);
  transpose_cvt<<<dim3(48, 16), 256, 0, stream>>>(Wqkv, Wqkvt, 512, 1536);
  transpose_cvt<<<dim3(16, 16), 256, 0, stream>>>(Wproj, Wprojt, 512, 512);
  cvt_x0<<<2048, 256, 0, stream>>>(x0, Rh);

  gemm_qkv_mfma<<<dim3(12, 254), 256, 0, stream>>>(Rh, Wqkvt, bqkv, Qh, KhU, VhU);
  gemm_pooled<<<dim3(12, 16), 256, 0, stream>>>(x1, Wqkv, bqkv,
                                                KhU + (size_t)PROW * CDIM,
                                                VhU + (size_t)PROW * CDIM);
  attn_kernel<<<dim3(144, 4, 2), 256, 0, stream>>>(Qh, KhU, VhU, Tok, WMaskP, Rh);
  gemm_proj_mfma<<<dim3(4, 254), 256, 0, stream>>>(Rh, Wprojt, bproj, out);
}

// Round 8
// 446.586 us; speedup vs baseline: 1.0939x; 1.0123x over previous
//
#include <hip/hip_runtime.h>

typedef _Float16 h16;
typedef __attribute__((ext_vector_type(8))) _Float16 half8;
typedef __attribute__((ext_vector_type(2))) _Float16 half2v;
typedef __attribute__((ext_vector_type(4))) float float4v;

typedef const __attribute__((address_space(1))) unsigned char gu8;
typedef __attribute__((address_space(3))) unsigned char su8;

#define NTOK  32400   // 5*60*108
#define NPTOK 720     // 5*12*12
#define CDIM  512
#define SCALE 0.08838834764831845f
#define ZROW  NTOK            // zero row index in unified K/V buffers
#define PROW  (NTOK + 1)      // pooled rows start

// valid-index table for the rolled halo (nonzero of stacked tl,tr,bl,br 5x9 masks)
__constant__ int VIR_TBL[120] = {
  5,6,7,8, 14,15,16,17, 23,24,25,26,
  27,28,29,30,31,32,33,34,35, 36,37,38,39,40,41,42,43,44,
  45,46,47,48, 54,55,56,57, 63,64,65,66,
  72,73,74,75,76,77,78,79,80, 81,82,83,84,85,86,87,88,89,
  90,91,92,93,94,95,96,97,98, 99,100,101,102,103,104,105,106,107,
  113,114,115,116, 122,123,124,125, 131,132,133,134,
  135,136,137,138,139,140,141,142,143, 144,145,146,147,148,149,150,151,152,
  153,154,155,156, 162,163,164,165, 171,172,173,174
};

// ---------------- token row table + per-step valid mask -------------------
// (zero_rows folded into block 0 to save one launch)
__global__ __launch_bounds__(256) void build_tok(int* __restrict__ Tok,
                                                 int* __restrict__ WMask,
                                                 h16* __restrict__ Kz,
                                                 h16* __restrict__ Vz) {
  const int win = blockIdx.x;
  const int wy = win / 12, wx = win % 12;
  if (win == 0) {
    for (int k = threadIdx.x; k < 512; k += 256) {
      Kz[(size_t)ZROW * CDIM + k] = (h16)0.f;
      Vz[(size_t)ZROW * CDIM + k] = (h16)0.f;
    }
  }
  for (int kidx = threadIdx.x; kidx < 1056; kidx += 256) {
    int e;
    if (kidx < 225) {
      int t = kidx / 45, pos = kidx % 45;
      int y = wy * 5 + pos / 9, x = wx * 9 + pos % 9;
      e = (t * 60 + y) * 108 + x;
    } else if (kidx < 825) {
      int jj = kidx - 225;
      int t = jj / 120, m = jj % 120;
      int vir = VIR_TBL[m];
      int p = vir / 45, pos = vir % 45;
      int r = pos / 9, c = pos % 9;
      int sy = (p < 2) ? -2 : 2;
      int sx = (p & 1) ? 4 : -4;
      int y = (wy * 5 + r - sy + 60) % 60;
      int x = (wx * 9 + c - sx + 108) % 108;
      e = (t * 60 + y) * 108 + x;
    } else if (kidx < 1050) {
      int jp = kidx - 825;
      int t = jp / 45, pos = jp % 45;
      int py = wy + pos / 9 - 2;
      int px = wx + pos % 9 - 4;
      e = (py >= 0 && py < 12 && px >= 0 && px < 12)
            ? (PROW + t * 144 + py * 12 + px) : ZROW;
    } else {
      e = ZROW;
    }
    Tok[win * 1056 + kidx] = e;
  }
  if (threadIdx.x < 33) {
    int m = 0;
#pragma unroll 1
    for (int r = 0; r < 32; r++) {
      int kidx = threadIdx.x * 32 + r;
      bool v;
      if (kidx < 825) v = true;
      else if (kidx < 1050) {
        int jp = kidx - 825, pos = jp % 45;
        int py = wy + pos / 9 - 2, px = wx + pos % 9 - 4;
        v = (py >= 0 && py < 12 && px >= 0 && px < 12);
      } else v = false;
      m |= (v ? 1 : 0) << r;
    }
    WMask[win * 33 + threadIdx.x] = m;
  }
}

// ------------- transpose_cvt: src R x C fp32 -> dst C x R f16 ------------
__global__ __launch_bounds__(256) void transpose_cvt(const float* __restrict__ src,
                                                     h16* __restrict__ dst,
                                                     int R, int C) {
  __shared__ float T[32][33];
  const int t = threadIdx.x;
  const int ct = blockIdx.x * 32;
  const int rt = blockIdx.y * 32;
  const int c = t & 31, r0 = (t >> 5) * 4;
#pragma unroll
  for (int i = 0; i < 4; i++)
    T[r0 + i][c] = src[(size_t)(rt + r0 + i) * C + ct + c];
  __syncthreads();
#pragma unroll
  for (int i = 0; i < 4; i++)
    dst[(size_t)(ct + r0 + i) * R + rt + c] = (h16)T[c][r0 + i];
}

// ------------- cvt_x0: fp32 (NTOK x 512) -> f16 --------------------------
__global__ __launch_bounds__(256) void cvt_x0(const float* __restrict__ src,
                                              h16* __restrict__ dst) {
  const int total = NTOK * CDIM / 8;
  for (int i = blockIdx.x * 256 + threadIdx.x; i < total; i += gridDim.x * 256) {
    const float4* s = (const float4*)(src + (size_t)i * 8);
    float4 f0 = s[0], f1 = s[1];
    half8 h;
    h[0] = (h16)f0.x; h[1] = (h16)f0.y; h[2] = (h16)f0.z; h[3] = (h16)f0.w;
    h[4] = (h16)f1.x; h[5] = (h16)f1.y; h[6] = (h16)f1.z; h[7] = (h16)f1.w;
    *(half8*)(dst + (size_t)i * 8) = h;
  }
}

// ------------ MFMA GEMM LDS shapes (triple-buffered, counted vmcnt) ------
// Granule swizzle p = g ^ ((row>>1)&3) on the global source + fragment read
// (both-sides rule) kills the 8-way fragment-read conflict [r5: -19us].
// T3/T4: 3 buffers + counted s_waitcnt vmcnt(4) + raw s_barrier.
// Per step kt: wait vmcnt(4) (own stage-kt loads landed; stage kt+1 stays
// in flight -- oldest-first vmcnt semantics), lgkmcnt(0) (own ds_reads done
// -> WAR on the buffer stage kt+2 overwrites), s_barrier (now ALL waves'
// stage-kt data resident + all readers drained), issue stage kt+2, compute
// buf[kt%3]. Never drains vmcnt to 0 in the loop -- removes the ~300-500
// cyc/step exposed HBM latency of the 2-phase version's barrier drain.
struct __align__(16) Stage3 { h16 Ah[3][128][32]; h16 Bh[3][128][32]; };  // 48 KB
union __align__(16) GemmLDSQ { Stage3 s; h16 Cs[128][136]; };             // 48 KB

// GEMM 1: Xh(f16) @ Wqkvt^T + b -> Q,K,V (f16). Bt layout [n][k].
__global__ __launch_bounds__(256) void gemm_qkv_mfma(
    const h16* __restrict__ A, const h16* __restrict__ Bt,
    const float* __restrict__ bias,
    h16* __restrict__ Q, h16* __restrict__ K, h16* __restrict__ V)
{
  __shared__ GemmLDSQ u;
  const int tid = threadIdx.x;
  const int lane = tid & 63, wv = tid >> 6;
  const int col = lane & 15, quad = lane >> 4;
  const int bn = blockIdx.x, bm = blockIdx.y;
  const int mo = (wv & 1) * 64, no = (wv >> 1) * 64;

  float4v acc[4][4];
#pragma unroll
  for (int i = 0; i < 4; i++)
#pragma unroll
    for (int j = 0; j < 4; j++) acc[i][j] = (float4v){0.f, 0.f, 0.f, 0.f};

  const int lrow = lane >> 2;
  const int lcol = (((lane & 3) ^ ((lane >> 3) & 3)) * 8);  // swizzled source granule
  const int arow = bm * 128 + wv * 32 + lrow;
  const int ar = arow < NTOK ? arow : (NTOK - 1);
  const int ar2 = (arow + 16) < NTOK ? (arow + 16) : (NTOK - 1);
  const h16* Ag  = A + (size_t)ar * 512 + lcol;
  const h16* Ag2 = A + (size_t)ar2 * 512 + lcol;
  const h16* Bg  = Bt + (size_t)(bn * 128 + wv * 32 + lrow) * 512 + lcol;

#define STAGE_G(buf, k0) do {                                              \
    su8* Al = (su8*)&u.s.Ah[buf][wv * 32][0];                              \
    su8* Bl = (su8*)&u.s.Bh[buf][wv * 32][0];                              \
    __builtin_amdgcn_global_load_lds((gu8*)(Ag + (k0)),            Al,        16, 0, 0); \
    __builtin_amdgcn_global_load_lds((gu8*)(Ag2 + (k0)),           Al + 1024, 16, 0, 0); \
    __builtin_amdgcn_global_load_lds((gu8*)(Bg + (k0)),            Bl,        16, 0, 0); \
    __builtin_amdgcn_global_load_lds((gu8*)(Bg + (k0) + 16 * 512), Bl + 1024, 16, 0, 0); \
  } while (0)

#define QSTEP(bufc, kt, bufs, vmc) do {                                    \
    asm volatile("s_waitcnt vmcnt(" #vmc ")" ::: "memory");                \
    asm volatile("s_waitcnt lgkmcnt(0)" ::: "memory");                     \
    __builtin_amdgcn_s_barrier();                                          \
    if ((kt) + 2 < 16) STAGE_G(bufs, ((kt) + 2) * 32);                     \
    half8 afr[4], bfr[4];                                                  \
    _Pragma("unroll")                                                      \
    for (int i = 0; i < 4; i++)                                            \
      afr[i] = *(const half8*)&u.s.Ah[bufc][mo + i * 16 + col][fsw];       \
    _Pragma("unroll")                                                      \
    for (int j = 0; j < 4; j++)                                            \
      bfr[j] = *(const half8*)&u.s.Bh[bufc][no + j * 16 + col][fsw];       \
    _Pragma("unroll")                                                      \
    for (int i = 0; i < 4; i++)                                            \
      _Pragma("unroll")                                                    \
      for (int j = 0; j < 4; j++)                                          \
        acc[i][j] = __builtin_amdgcn_mfma_f32_16x16x32_f16(afr[i], bfr[j], acc[i][j], 0, 0, 0); \
  } while (0)

  const int fsw = (quad ^ ((col >> 1) & 3)) * 8;  // swizzled fragment granule
  STAGE_G(0, 0);
  STAGE_G(1, 32);
#pragma unroll 1
  for (int kb = 0; kb < 5; kb++) {
    const int kt = kb * 3;
    QSTEP(0, kt,     2, 4);
    QSTEP(1, kt + 1, 0, 4);
    QSTEP(2, kt + 2, 1, 4);
  }
  QSTEP(0, 15, 0, 0);   // kt+2 >= 16: no stage; full drain before last tile

  __syncthreads();
  float bv[4];
#pragma unroll
  for (int j = 0; j < 4; j++) bv[j] = bias[bn * 128 + no + j * 16 + col];
#pragma unroll
  for (int i = 0; i < 4; i++)
#pragma unroll
    for (int j = 0; j < 4; j++)
#pragma unroll
      for (int r = 0; r < 4; r++)
        u.Cs[mo + i * 16 + quad * 4 + r][no + j * 16 + col] = (h16)(acc[i][j][r] + bv[j]);
  __syncthreads();

  const int row_l = tid >> 1, halfseg = (tid & 1) * 64;
  const int row_g = bm * 128 + row_l;
  const int jsel = bn >> 2;
  const int ch0 = (bn & 3) * 128 + halfseg;
  h16* dst = (jsel == 0) ? Q : (jsel == 1) ? K : V;
  if (row_g < NTOK) {
#pragma unroll
    for (int c = 0; c < 64; c += 8)
      *(half8*)&dst[(size_t)row_g * 512 + ch0 + c] = *(const half8*)&u.Cs[row_l][halfseg + c];
  }
}

// GEMM 3: AO(f16) @ Wprojt^T + b -> out (fp32). Same 3-buf counted-vmcnt.
__global__ __launch_bounds__(256) void gemm_proj_mfma(
    const h16* __restrict__ A, const h16* __restrict__ Bt,
    const float* __restrict__ bias, float* __restrict__ out)
{
  __shared__ Stage3 s;
  const int tid = threadIdx.x;
  const int lane = tid & 63, wv = tid >> 6;
  const int col = lane & 15, quad = lane >> 4;
  const int bn = blockIdx.x, bm = blockIdx.y;
  const int mo = (wv & 1) * 64, no = (wv >> 1) * 64;

  float4v acc[4][4];
#pragma unroll
  for (int i = 0; i < 4; i++)
#pragma unroll
    for (int j = 0; j < 4; j++) acc[i][j] = (float4v){0.f, 0.f, 0.f, 0.f};

  const int lrow = lane >> 2;
  const int lcol = (((lane & 3) ^ ((lane >> 3) & 3)) * 8);
  const int arow = bm * 128 + wv * 32 + lrow;
  const int ar = arow < NTOK ? arow : (NTOK - 1);
  const int ar2 = (arow + 16) < NTOK ? (arow + 16) : (NTOK - 1);
  const h16* Ag  = A + (size_t)ar * 512 + lcol;
  const h16* Ag2 = A + (size_t)ar2 * 512 + lcol;
  const h16* Bg  = Bt + (size_t)(bn * 128 + wv * 32 + lrow) * 512 + lcol;

#define STAGE_P(buf, k0) do {                                              \
    su8* Al = (su8*)&s.Ah[buf][wv * 32][0];                                \
    su8* Bl = (su8*)&s.Bh[buf][wv * 32][0];                                \
    __builtin_amdgcn_global_load_lds((gu8*)(Ag + (k0)),            Al,        16, 0, 0); \
    __builtin_amdgcn_global_load_lds((gu8*)(Ag2 + (k0)),           Al + 1024, 16, 0, 0); \
    __builtin_amdgcn_global_load_lds((gu8*)(Bg + (k0)),            Bl,        16, 0, 0); \
    __builtin_amdgcn_global_load_lds((gu8*)(Bg + (k0) + 16 * 512), Bl + 1024, 16, 0, 0); \
  } while (0)

#define PSTEP(bufc, kt, bufs, vmc) do {                                    \
    asm volatile("s_waitcnt vmcnt(" #vmc ")" ::: "memory");                \
    asm volatile("s_waitcnt lgkmcnt(0)" ::: "memory");                     \
    __builtin_amdgcn_s_barrier();                                          \
    if ((kt) + 2 < 16) STAGE_P(bufs, ((kt) + 2) * 32);                     \
    half8 afr[4], bfr[4];                                                  \
    _Pragma("unroll")                                                      \
    for (int i = 0; i < 4; i++)                                            \
      afr[i] = *(const half8*)&s.Ah[bufc][mo + i * 16 + col][fsw];         \
    _Pragma("unroll")                                                      \
    for (int j = 0; j < 4; j++)                                            \
      bfr[j] = *(const half8*)&s.Bh[bufc][no + j * 16 + col][fsw];         \
    _Pragma("unroll")                                                      \
    for (int i = 0; i < 4; i++)                                            \
      _Pragma("unroll")                                                    \
      for (int j = 0; j < 4; j++)                                          \
        acc[i][j] = __builtin_amdgcn_mfma_f32_16x16x32_f16(afr[i], bfr[j], acc[i][j], 0, 0, 0); \
  } while (0)

  const int fsw = (quad ^ ((col >> 1) & 3)) * 8;
  STAGE_P(0, 0);
  STAGE_P(1, 32);
#pragma unroll 1
  for (int kb = 0; kb < 5; kb++) {
    const int kt = kb * 3;
    PSTEP(0, kt,     2, 4);
    PSTEP(1, kt + 1, 0, 4);
    PSTEP(2, kt + 2, 1, 4);
  }
  PSTEP(0, 15, 0, 0);

  float bv[4];
#pragma unroll
  for (int j = 0; j < 4; j++) bv[j] = bias[bn * 128 + no + j * 16 + col];
#pragma unroll
  for (int i = 0; i < 4; i++) {
#pragma unroll
    for (int r = 0; r < 4; r++) {
      int row_g = bm * 128 + mo + i * 16 + quad * 4 + r;
      if (row_g < NTOK) {
#pragma unroll
        for (int j = 0; j < 4; j++)
          out[(size_t)row_g * 512 + bn * 128 + no + j * 16 + col] = acc[i][j][r] + bv[j];
      }
    }
  }
}

// ---------------- GEMM 2: pooled x1 @ W_qkv[:,512:] -> Kp,Vp -------------
__global__ __launch_bounds__(256) void gemm_pooled(
    const float* __restrict__ A, const float* __restrict__ B,
    const float* __restrict__ bias,
    h16* __restrict__ Kp, h16* __restrict__ Vp)
{
  __shared__ float As[64][17];
  __shared__ float Bs[16][64];
  const int tid = threadIdx.x;
  const int bm = blockIdx.x, bn = blockIdx.y;
  const int tm = tid >> 4, tn = tid & 15;
  const int lrow = tid >> 2, lk = (tid & 3) * 4;
  const int brow = tid >> 4, bcol = (tid & 15) * 4;
  float acc[4][4] = {};
  const int orow = bm * 64 + lrow;
  int srow = 0;
  if (orow < NPTOK) { int t = orow / 144, rem = orow % 144; srow = rem * 5 + t; }
  const float* Ap = A + (size_t)srow * 512 + lk;
  const float* Bp = B + (size_t)brow * 1536 + 512 + bn * 64 + bcol;

  for (int k0 = 0; k0 < 512; k0 += 16) {
    float4 av = make_float4(0.f, 0.f, 0.f, 0.f);
    if (orow < NPTOK) av = *(const float4*)(Ap + k0);
    float4 bv = *(const float4*)(Bp + (size_t)k0 * 1536);
    As[lrow][lk + 0] = av.x; As[lrow][lk + 1] = av.y;
    As[lrow][lk + 2] = av.z; As[lrow][lk + 3] = av.w;
    *(float4*)&Bs[brow][bcol] = bv;
    __syncthreads();
#pragma unroll
    for (int kk = 0; kk < 16; kk++) {
      float a[4];
#pragma unroll
      for (int i = 0; i < 4; i++) a[i] = As[tm * 4 + i][kk];
      float4 b = *(const float4*)&Bs[kk][tn * 4];
#pragma unroll
      for (int i = 0; i < 4; i++) {
        acc[i][0] = fmaf(a[i], b.x, acc[i][0]);
        acc[i][1] = fmaf(a[i], b.y, acc[i][1]);
        acc[i][2] = fmaf(a[i], b.z, acc[i][2]);
        acc[i][3] = fmaf(a[i], b.w, acc[i][3]);
      }
    }
    __syncthreads();
  }
  const int nl = bn * 64 + tn * 4;
  const int j = nl >> 9;
  const int ch = nl & 511;
  h16* dst = (j == 0) ? Kp : Vp;
#pragma unroll
  for (int i = 0; i < 4; i++) {
    int r = bm * 64 + tm * 4 + i;
    if (r < NPTOK) {
#pragma unroll
      for (int c = 0; c < 4; c++)
        dst[(size_t)r * 512 + ch + c] = (h16)(acc[i][c] + bias[512 + nl + c]);
    }
  }
}

// ---------------- Attention (round-3 best: ~174us, unchanged) ------------
// grid (144 win, 4 head, 2 qgroup), 256 thr / 4 waves; wave owns 2 q-tiles.
// S^T = K.Q^T operand-swapped MFMA; fixed-max softmax; P^T->A-frag via 8
// packed shuffles. LDS double-buffer, 1 barrier/step; setprio around MFMA.
// Ks stride 136 h16: S^T reads are ~2-way (free); r5's 128+XOR left the
// conflict counter EXACTLY unchanged and cost 20% -- do not re-touch.
// launch_bounds(256,3): (256,4) -> 64-VGPR cap -> scratch spill (r2, 2.6x).
// 8-wave merge (r4): halved traffic, starved TLP, -17%. Do not re-merge.
__global__ __launch_bounds__(256, 3) void attn_kernel(
    const h16* __restrict__ Qh, const h16* __restrict__ KhU,
    const h16* __restrict__ VhU, const int* __restrict__ Tok,
    const int* __restrict__ WMask, h16* __restrict__ AOh)
{
  __shared__ __align__(16) h16 Ks[2][32 * 136];
  __shared__ __align__(16) h16 Vt[2][128 * 40];

  const int tid = threadIdx.x;
  const int lane = tid & 63;
  const int wv = tid >> 6;
  const int win = blockIdx.x;
  const int head = blockIdx.y;
  const int qg = blockIdx.z;
  const int wy = win / 12, wx = win % 12;
  const int col = lane & 15;
  const int quad = lane >> 4;
  const int* TokW = Tok + win * 1056;
  const int* WMaskW = WMask + win * 33;

  // ---- Q fragments for 2 tiles ----
  half8 qfrag[2][4];
  const int tile0 = qg * 8 + wv * 2;
#pragma unroll
  for (int tt = 0; tt < 2; tt++) {
    int qrow = (tile0 + tt) * 16 + col;
    if (qrow < 225) {
      int t = qrow / 45, pos = qrow % 45;
      int y = wy * 5 + pos / 9, x = wx * 9 + pos % 9;
      const h16* qsrc = Qh + (size_t)((t * 60 + y) * 108 + x) * CDIM + head * 128;
#pragma unroll
      for (int dc = 0; dc < 4; dc++)
        qfrag[tt][dc] = *(const half8*)(qsrc + dc * 32 + quad * 8);
    } else {
#pragma unroll
      for (int dc = 0; dc < 4; dc++)
#pragma unroll
        for (int jj = 0; jj < 8; jj++) qfrag[tt][dc][jj] = (h16)0.f;
    }
  }

  float4v O[2][8];
#pragma unroll
  for (int tt = 0; tt < 2; tt++)
#pragma unroll
    for (int i = 0; i < 8; i++) O[tt][i] = (float4v){0.f, 0.f, 0.f, 0.f};
  float lp[2] = {0.f, 0.f};

  // staging roles
  const int krow = tid >> 3, kseg = tid & 7;
  const int vrp = tid >> 4, vcg = tid & 15;
  const int kch = head * 128 + kseg * 16;
  const int vch = head * 128 + vcg * 8;
  const int rp = (vrp + (vcg & 3) * 4) & 15;

  // ---- prologue: gather+stage step0 into buf0; gather step1 into regs ----
  {
    const h16* ks = KhU + (size_t)TokW[krow] * CDIM + kch;
    half8 k0c = *(const half8*)ks;
    half8 k1c = *(const half8*)(ks + 8);
    half8 vac = *(const half8*)(VhU + (size_t)TokW[2 * vrp] * CDIM + vch);
    half8 vbc = *(const half8*)(VhU + (size_t)TokW[2 * vrp + 1] * CDIM + vch);
    *(half8*)&Ks[0][krow * 136 + kseg * 16] = k0c;
    *(half8*)&Ks[0][krow * 136 + kseg * 16 + 8] = k1c;
#pragma unroll
    for (int i = 0; i < 8; i++) {
      half2v w; w[0] = vac[i]; w[1] = vbc[i];
      *(half2v*)&Vt[0][(vcg * 8 + i) * 40 + rp * 2] = w;
    }
  }
  half8 k0n, k1n, van, vbn;
  {
    const h16* ks = KhU + (size_t)TokW[32 + krow] * CDIM + kch;
    k0n = *(const half8*)ks;
    k1n = *(const half8*)(ks + 8);
    van = *(const half8*)(VhU + (size_t)TokW[32 + 2 * vrp] * CDIM + vch);
    vbn = *(const half8*)(VhU + (size_t)TokW[32 + 2 * vrp + 1] * CDIM + vch);
  }
  // token ring: slot (s&1) holds rows for step s+2 at the top of step s
  int tokK[2], tokVa[2], tokVb[2];
  tokK[0] = TokW[64 + krow]; tokVa[0] = TokW[64 + 2 * vrp]; tokVb[0] = TokW[64 + 2 * vrp + 1];
  tokK[1] = TokW[96 + krow]; tokVa[1] = TokW[96 + 2 * vrp]; tokVb[1] = TokW[96 + 2 * vrp + 1];
  __syncthreads();

  for (int step = 0; step < 33; ++step) {
    const int cur = step & 1;

    // ---- stage NEXT tile into the other buffer (overlaps compute) ----
    if (step + 1 < 33) {
      h16* KsN = Ks[cur ^ 1];
      h16* VtN = Vt[cur ^ 1];
      *(half8*)&KsN[krow * 136 + kseg * 16] = k0n;
      *(half8*)&KsN[krow * 136 + kseg * 16 + 8] = k1n;
#pragma unroll
      for (int i = 0; i < 8; i++) {
        half2v w; w[0] = van[i]; w[1] = vbn[i];
        *(half2v*)&VtN[(vcg * 8 + i) * 40 + rp * 2] = w;
      }
    }
    // ---- issue gathers for step+2 (latency hidden under compute) ----
    if (step + 2 < 33) {
      const h16* ks = KhU + (size_t)tokK[cur] * CDIM + kch;
      k0n = *(const half8*)ks;
      k1n = *(const half8*)(ks + 8);
      van = *(const half8*)(VhU + (size_t)tokVa[cur] * CDIM + vch);
      vbn = *(const half8*)(VhU + (size_t)tokVb[cur] * CDIM + vch);
      if (step + 4 < 33) {
        tokK[cur]  = TokW[(step + 4) * 32 + krow];
        tokVa[cur] = TokW[(step + 4) * 32 + 2 * vrp];
        tokVb[cur] = TokW[(step + 4) * 32 + 2 * vrp + 1];
      }
    }

    const int mask = WMaskW[step];
    const h16* KsC = Ks[cur];
    const h16* VtC = Vt[cur];

    // ---- S^T = K.Q^T (operand-swapped) ----
    float4v s0[2] = {{0.f,0.f,0.f,0.f},{0.f,0.f,0.f,0.f}};
    float4v s1[2] = {{0.f,0.f,0.f,0.f},{0.f,0.f,0.f,0.f}};
    __builtin_amdgcn_s_setprio(1);
#pragma unroll
    for (int dc = 0; dc < 4; dc++) {
      half8 a0 = *(const half8*)&KsC[col * 136 + dc * 32 + quad * 8];
      half8 a1 = *(const half8*)&KsC[(col + 16) * 136 + dc * 32 + quad * 8];
#pragma unroll
      for (int tt = 0; tt < 2; tt++) {
        s0[tt] = __builtin_amdgcn_mfma_f32_16x16x32_f16(a0, qfrag[tt][dc], s0[tt], 0, 0, 0);
        s1[tt] = __builtin_amdgcn_mfma_f32_16x16x32_f16(a1, qfrag[tt][dc], s1[tt], 0, 0, 0);
      }
    }
    __builtin_amdgcn_s_setprio(0);

    // ---- fixed-max softmax + P^T -> A-frag via shuffles ----
    half8 pfrag[2];
    const int srcA = (((quad << 1) & 3) << 4) | col;
    const int srcB = ((((quad << 1) + 1) & 3) << 4) | col;
    const bool hi = quad >= 2;
#pragma unroll
    for (int tt = 0; tt < 2; tt++) {
      float pm0[4], pm1[4];
#pragma unroll
      for (int i = 0; i < 4; i++) {
        int r = quad * 4 + i;
        float e0 = __expf(s0[tt][i] * SCALE);
        float e1 = __expf(s1[tt][i] * SCALE);
        pm0[i] = ((mask >> r) & 1) ? e0 : 0.f;
        pm1[i] = ((mask >> (16 + r)) & 1) ? e1 : 0.f;
        lp[tt] += pm0[i] + pm1[i];
      }
      float g00 = __builtin_bit_cast(float, __builtin_amdgcn_cvt_pkrtz(pm0[0], pm0[1]));
      float g01 = __builtin_bit_cast(float, __builtin_amdgcn_cvt_pkrtz(pm0[2], pm0[3]));
      float g10 = __builtin_bit_cast(float, __builtin_amdgcn_cvt_pkrtz(pm1[0], pm1[1]));
      float g11 = __builtin_bit_cast(float, __builtin_amdgcn_cvt_pkrtz(pm1[2], pm1[3]));
      float a0 = __shfl(g00, srcA), a1 = __shfl(g01, srcA);
      float a2 = __shfl(g00, srcB), a3 = __shfl(g01, srcB);
      float b0 = __shfl(g10, srcA), b1 = __shfl(g11, srcA);
      float b2 = __shfl(g10, srcB), b3 = __shfl(g11, srcB);
      float4v pf;
      pf[0] = hi ? b0 : a0;
      pf[1] = hi ? b1 : a1;
      pf[2] = hi ? b2 : a2;
      pf[3] = hi ? b3 : a3;
      pfrag[tt] = __builtin_bit_cast(half8, pf);
    }

    // ---- O += P V (shared V fragments, single b128 each) ----
    __builtin_amdgcn_s_setprio(1);
#pragma unroll
    for (int dt = 0; dt < 8; dt++) {
      int ch = dt * 16 + col;
      int g4 = ((dt * 2 + (col >> 3)) & 3) * 4;
      int x0 = (quad * 4 + g4) & 15;
      half8 vf = *(const half8*)&VtC[ch * 40 + x0 * 2];
#pragma unroll
      for (int tt = 0; tt < 2; tt++)
        O[tt][dt] = __builtin_amdgcn_mfma_f32_16x16x32_f16(pfrag[tt], vf, O[tt][dt], 0, 0, 0);
    }
    __builtin_amdgcn_s_setprio(0);

    // single barrier: covers RAW on buf[cur^1] writes and WAR on buf[cur] reads
    __syncthreads();
  }

  // ---- epilogue: deferred l reduction + store ----
#pragma unroll
  for (int tt = 0; tt < 2; tt++) {
    float l_all = lp[tt];
    l_all += __shfl_xor(l_all, 16);
    l_all += __shfl_xor(l_all, 32);
#pragma unroll
    for (int i = 0; i < 4; i++) {
      int qr = (tile0 + tt) * 16 + quad * 4 + i;
      if (qr < 225) {
        float invl = __builtin_amdgcn_rcpf(__shfl(l_all, quad * 4 + i));
        h16* dst = AOh + ((size_t)win * 225 + qr) * CDIM + head * 128 + col;
#pragma unroll
        for (int dt = 0; dt < 8; dt++)
          dst[dt * 16] = (h16)(O[tt][dt][i] * invl);
      }
    }
  }
}

extern "C" void kernel_launch(void* const* d_in, const int* in_sizes, int n_in,
                              void* d_out, int out_size, void* d_ws, size_t ws_size,
                              hipStream_t stream) {
  const float* x0    = (const float*)d_in[0];
  const float* x1    = (const float*)d_in[1];
  const float* Wqkv  = (const float*)d_in[2];
  const float* bqkv  = (const float*)d_in[3];
  const float* Wproj = (const float*)d_in[4];
  const float* bproj = (const float*)d_in[5];
  float* out = (float*)d_out;

  const size_t NU = (size_t)(NTOK + 1 + NPTOK);   // unified K/V row count
  h16* Qh   = (h16*)d_ws;
  h16* KhU  = Qh + (size_t)NTOK * CDIM;
  h16* VhU  = KhU + NU * CDIM;
  // Rh: NTOK x 512 f16 region, time-shared: x0h (GEMM1 input) then AOh
  h16* Rh   = VhU + NU * CDIM;
  h16* Wqkvt  = Rh + (size_t)NTOK * CDIM;         // 1536 x 512
  h16* Wprojt = Wqkvt + (size_t)1536 * 512;       // 512 x 512
  int* Tok    = (int*)(Wprojt + (size_t)512 * 512);  // 144 x 1056
  int* WMaskP = Tok + (size_t)144 * 1056;            // 144 x 33

  build_tok<<<144, 256, 0, stream>>>(Tok, WMaskP, KhU, VhU);
  transpose_cvt<<<dim3(48, 16), 256, 0, stream>>>(Wqkv, Wqkvt, 512, 1536);
  transpose_cvt<<<dim3(16, 16), 256, 0, stream>>>(Wproj, Wprojt, 512, 512);
  cvt_x0<<<2048, 256, 0, stream>>>(x0, Rh);

  gemm_qkv_mfma<<<dim3(12, 254), 256, 0, stream>>>(Rh, Wqkvt, bqkv, Qh, KhU, VhU);
  gemm_pooled<<<dim3(12, 16), 256, 0, stream>>>(x1, Wqkv, bqkv,
                                                KhU + (size_t)PROW * CDIM,
                                                VhU + (size_t)PROW * CDIM);
  attn_kernel<<<dim3(144, 4, 2), 256, 0, stream>>>(Qh, KhU, VhU, Tok, WMaskP, Rh);
  gemm_proj_mfma<<<dim3(4, 254), 256, 0, stream>>>(Rh, Wprojt, bproj, out);
}